// Round 9
// baseline (664.402 us; speedup 1.0000x reference)
//
#include <hip/hip_runtime.h>
#include <hip/hip_bf16.h>
#include <stdint.h>

typedef __hip_bfloat16 bf16;
typedef __attribute__((ext_vector_type(8))) __bf16 bf16x8;
typedef __attribute__((ext_vector_type(4))) float f32x4;

#define D_MODEL 1024
#define NHEAD   16
#define HDIM    64
#define DFF     4096
#define BATCH   16
#define SEQ     512
#define MROWS   (BATCH*SEQ)   // 8192

__device__ __forceinline__ float b2f_bits(unsigned short u) {
    return __uint_as_float(((unsigned)u) << 16);
}
__device__ __forceinline__ bf16 f2b(float v) { return __float2bfloat16(v); }
__device__ __forceinline__ unsigned short f2b_bits(float v) {
    bf16 t = __float2bfloat16(v);
    return *(unsigned short*)&t;
}
// async global->LDS, 16B per lane (dest = wave-uniform base + lane*16)
__device__ __forceinline__ void gll16(void* lds, const void* gsrc) {
    __builtin_amdgcn_global_load_lds(
        (const __attribute__((address_space(1))) unsigned*)gsrc,
        (__attribute__((address_space(3))) unsigned*)lds,
        16, 0, 0);
}
// exact-enough GELU: tanh form, max |err| ~3e-4 vs erf form (ok at bf16 out)
__device__ __forceinline__ float gelu_f(float u) {
    float z  = 0.7978845608028654f * (u + 0.044715f * u * u * u);
    float az = fabsf(z);
    float e  = __expf(-2.0f * az);
    float th = (1.0f - e) / (1.0f + e);
    th = copysignf(th, z);
    return 0.5f * u * (1.0f + th);
}

// ---------------------------------------------------------------------------
// fp32 -> bf16 weight conversion (n multiple of 4; grid covers exactly n/4)
// ---------------------------------------------------------------------------
__global__ __launch_bounds__(256)
void cvt_kernel(const float* __restrict__ in, bf16* __restrict__ out, int n)
{
    int i = (blockIdx.x * 256 + threadIdx.x) * 4;
    if (i >= n) return;
    float4 f = *(const float4*)(in + i);
    ushort4 o;
    o.x = f2b_bits(f.x); o.y = f2b_bits(f.y);
    o.z = f2b_bits(f.z); o.w = f2b_bits(f.w);
    *(ushort4*)((unsigned short*)out + i) = o;
}

// ---------------------------------------------------------------------------
// LayerNorm: fp32 in, bf16 out. One block (256 threads) per row of 1024.
// ---------------------------------------------------------------------------
__global__ __launch_bounds__(256)
void ln_kernel(const float* __restrict__ xin, const float* __restrict__ w,
               const float* __restrict__ b, bf16* __restrict__ out)
{
    int row  = blockIdx.x;
    int t    = threadIdx.x;
    int lane = t & 63, wv = t >> 6;
    int col  = t * 4;

    float4 f = *(const float4*)(xin + (size_t)row * D_MODEL + col);
    float v[4] = {f.x, f.y, f.z, f.w};

    float s  = v[0] + v[1] + v[2] + v[3];
    float ss = v[0]*v[0] + v[1]*v[1] + v[2]*v[2] + v[3]*v[3];
    #pragma unroll
    for (int m = 1; m < 64; m <<= 1) {
        s  += __shfl_xor(s,  m, 64);
        ss += __shfl_xor(ss, m, 64);
    }
    __shared__ float rs0[4], rs1[4];
    if (lane == 0) { rs0[wv] = s; rs1[wv] = ss; }
    __syncthreads();
    s  = rs0[0] + rs0[1] + rs0[2] + rs0[3];
    ss = rs1[0] + rs1[1] + rs1[2] + rs1[3];

    float mu  = s * (1.0f / D_MODEL);
    float var = ss * (1.0f / D_MODEL) - mu * mu;
    float rs  = rsqrtf(var + 1e-5f);

    float4 wf = *(const float4*)(w + col);
    float4 bf = *(const float4*)(b + col);
    ushort4 o;
    o.x = f2b_bits((v[0]-mu)*rs*wf.x + bf.x);
    o.y = f2b_bits((v[1]-mu)*rs*wf.y + bf.y);
    o.z = f2b_bits((v[2]-mu)*rs*wf.z + bf.z);
    o.w = f2b_bits((v[3]-mu)*rs*wf.w + bf.w);
    *(ushort4*)((unsigned short*)out + (size_t)row * D_MODEL + col) = o;
}

// ---------------------------------------------------------------------------
// gemm8: 256x256 tile, BK=64, 512 thr = 8 waves (2x4), phase-interleaved
// schedule with counted vmcnt (T3+T4), source-pre-swizzled LDS (T2, rule #21),
// setprio around MFMA (T5). C[M,N] = A[M,K]*Bw[N,K]^T + bias.
//   EPI 1: + fast GELU -> bf16 out (LDS-staged coalesced store)
//   EPI 3: -> scatter bf16 Q/K/VT (qkv projection)
// LDS 128 KB: 2 buf x (A[256][64] + B[256][64]) bf16, each split in k-halves
// of 32 cols (16 KB, = 2 gll16/thread). Swizzle: 64-B rows, 4 granules;
// LDS granule slot = q ^ ((row>>1)&3) on BOTH the pre-swizzled global source
// and the ds_read address -> residual 2-way conflict (free, m136).
// Per K-tile: 4 phases {stage 1 half || ds_read subtile || s_barrier ||
// setprio(1) 16 MFMA setprio(0) || s_barrier}; phases stage A0',B0',A1',B1'.
// s_waitcnt vmcnt(4) ONLY at end of ph1/ph3: at each wait the 8 outstanding
// loads are the next halves; draining to 4 completes exactly the two halves
// needed two phases later (per-wave count + shared barrier => collective).
// Raw s_barrier (not __syncthreads) so the DMA queue is never drained to 0.
// Per-wave output 128x64: acc[8][4], m = mb+wm*128+i*16+q*4+rr,
// n = nb+wn*64+j*16+r (C/D: col=lane&15, row=(lane>>4)*4+reg, m89/m91).
// M,N mult of 256; K mult of 64; nwg mult of 8 (XCD swizzle T1).
// ---------------------------------------------------------------------------
template<int EPI>
__global__ __launch_bounds__(512, 2)
void gemm8(const bf16* __restrict__ A, const bf16* __restrict__ Bw,
           const float* __restrict__ bias, void* __restrict__ Cout,
           bf16* __restrict__ qb, bf16* __restrict__ ktb,
           bf16* __restrict__ vb, int M, int N, int K)
{
    constexpr int BUFSZ = 65536;     // A 32K + B 32K per buffer
    __shared__ char smem[131072];

    int t = threadIdx.x;
    int lane = t & 63, wid = t >> 6;
    int wm = wid >> 2, wn = wid & 3;
    int r = lane & 15, q = lane >> 4;

    // XCD swizzle (bijective: nwg % 8 == 0)
    int gx  = gridDim.x;
    int L   = blockIdx.y * gx + blockIdx.x;
    int qq  = (gx * gridDim.y) >> 3;
    int nid = (L & 7) * qq + (L >> 3);
    int mb  = (nid / gx) * 256, nb = (nid % gx) * 256;

    const char* Ag = (const char*)A + (size_t)mb * K * 2;
    const char* Bg = (const char*)Bw + (size_t)nb * K * 2;

    // staging geometry: half = 256 rows x 32 k-cols = 16 KB = 2 gll16/thread.
    // dest linear (g*16); source granule pre-swizzled j = (g&3) ^ ((row>>1)&3)
    int g0r = t >> 2,   g0j = (t & 3) ^ ((g0r >> 1) & 3);
    int g1r = g0r + 128, g1j = (t & 3) ^ ((g1r >> 1) & 3);
    size_t a0 = (size_t)g0r * K * 2 + (size_t)g0j * 16;
    size_t a1 = (size_t)g1r * K * 2 + (size_t)g1j * 16;

    // mat 0=A,1=B; h = k-half; T = K-tile; b = buffer
    #define STG(mat, h, T, b) do {                                       \
        char* d = smem + (b) * BUFSZ + (mat) * 32768 + (h) * 16384;      \
        const char* s = (mat) ? Bg : Ag;                                 \
        size_t ko = ((size_t)(T) * 64 + (h) * 32) * 2;                   \
        gll16(d + t * 16,        s + a0 + ko);                           \
        gll16(d + 8192 + t * 16, s + a1 + ko);                           \
    } while (0)

    f32x4 acc[8][4] = {};
    int NT = K >> 6;
    int rowA = wm * 128 + r;     // + i*16 (+64 for upper half)
    int rowB = wn * 64 + r;      // + j*16

    // prologue: tile 0's 4 halves; vmcnt(4) -> A0,B0 landed
    STG(0, 0, 0, 0); STG(1, 0, 0, 0); STG(0, 1, 0, 0); STG(1, 1, 0, 0);
    asm volatile("s_waitcnt vmcnt(4)" ::: "memory");
    __builtin_amdgcn_s_barrier();

    for (int T = 0; T < NT; ++T) {
        const char* Ab = smem + (T & 1) * BUFSZ;
        const char* Bb = Ab + 32768;
        bool pf = (T + 1 < NT);
        int bn = (T & 1) ^ 1;

        bf16x8 af[4], bfq[4];

        // ---- ph0: kk=0, i 0..3 ----
        if (pf) STG(0, 0, T + 1, bn);
        #pragma unroll
        for (int i = 0; i < 4; i++) {
            int ro = rowA + i * 16;
            af[i] = *(const bf16x8*)(Ab + ro * 64 + ((q ^ ((ro >> 1) & 3)) << 4));
        }
        #pragma unroll
        for (int j = 0; j < 4; j++) {
            int ro = rowB + j * 16;
            bfq[j] = *(const bf16x8*)(Bb + ro * 64 + ((q ^ ((ro >> 1) & 3)) << 4));
        }
        __builtin_amdgcn_s_barrier();
        __builtin_amdgcn_s_setprio(1);
        #pragma unroll
        for (int i = 0; i < 4; i++)
            #pragma unroll
            for (int j = 0; j < 4; j++)
                acc[i][j] = __builtin_amdgcn_mfma_f32_16x16x32_bf16(af[i], bfq[j], acc[i][j], 0, 0, 0);
        __builtin_amdgcn_s_setprio(0);
        __builtin_amdgcn_s_barrier();

        // ---- ph1: kk=0, i 4..7 ----
        if (pf) STG(1, 0, T + 1, bn);
        #pragma unroll
        for (int i = 0; i < 4; i++) {
            int ro = rowA + 64 + i * 16;
            af[i] = *(const bf16x8*)(Ab + ro * 64 + ((q ^ ((ro >> 1) & 3)) << 4));
        }
        __builtin_amdgcn_s_barrier();
        __builtin_amdgcn_s_setprio(1);
        #pragma unroll
        for (int i = 0; i < 4; i++)
            #pragma unroll
            for (int j = 0; j < 4; j++)
                acc[i + 4][j] = __builtin_amdgcn_mfma_f32_16x16x32_bf16(af[i], bfq[j], acc[i + 4][j], 0, 0, 0);
        __builtin_amdgcn_s_setprio(0);
        asm volatile("s_waitcnt vmcnt(4)" ::: "memory");   // A1(T),B1(T) landed
        __builtin_amdgcn_s_barrier();

        // ---- ph2: kk=1, i 0..3 ----
        if (pf) STG(0, 1, T + 1, bn);
        #pragma unroll
        for (int i = 0; i < 4; i++) {
            int ro = rowA + i * 16;
            af[i] = *(const bf16x8*)(Ab + 16384 + ro * 64 + ((q ^ ((ro >> 1) & 3)) << 4));
        }
        #pragma unroll
        for (int j = 0; j < 4; j++) {
            int ro = rowB + j * 16;
            bfq[j] = *(const bf16x8*)(Bb + 16384 + ro * 64 + ((q ^ ((ro >> 1) & 3)) << 4));
        }
        __builtin_amdgcn_s_barrier();
        __builtin_amdgcn_s_setprio(1);
        #pragma unroll
        for (int i = 0; i < 4; i++)
            #pragma unroll
            for (int j = 0; j < 4; j++)
                acc[i][j] = __builtin_amdgcn_mfma_f32_16x16x32_bf16(af[i], bfq[j], acc[i][j], 0, 0, 0);
        __builtin_amdgcn_s_setprio(0);
        __builtin_amdgcn_s_barrier();

        // ---- ph3: kk=1, i 4..7 ----
        if (pf) STG(1, 1, T + 1, bn);
        #pragma unroll
        for (int i = 0; i < 4; i++) {
            int ro = rowA + 64 + i * 16;
            af[i] = *(const bf16x8*)(Ab + 16384 + ro * 64 + ((q ^ ((ro >> 1) & 3)) << 4));
        }
        __builtin_amdgcn_s_barrier();
        __builtin_amdgcn_s_setprio(1);
        #pragma unroll
        for (int i = 0; i < 4; i++)
            #pragma unroll
            for (int j = 0; j < 4; j++)
                acc[i + 4][j] = __builtin_amdgcn_mfma_f32_16x16x32_bf16(af[i], bfq[j], acc[i + 4][j], 0, 0, 0);
        __builtin_amdgcn_s_setprio(0);
        asm volatile("s_waitcnt vmcnt(4)" ::: "memory");   // A0(T+1),B0(T+1) landed
        __builtin_amdgcn_s_barrier();
    }
    #undef STG

    if (EPI == 1) {
        // GELU + bf16, staged through LDS in two 128-row halves for
        // coalesced 16B/lane full-row stores (kills 32B-segment writeback)
        asm volatile("s_waitcnt vmcnt(0)" ::: "memory");
        __syncthreads();
        __bf16* Cs = (__bf16*)smem;
        char* Cg = (char*)Cout;
        #pragma unroll
        for (int hh = 0; hh < 2; ++hh) {
            if (wm == hh) {
                #pragma unroll
                for (int j = 0; j < 4; j++) {
                    int n = nb + wn * 64 + j * 16 + r;
                    float bv = bias[n];
                    #pragma unroll
                    for (int i = 0; i < 8; i++)
                        #pragma unroll
                        for (int rr = 0; rr < 4; rr++) {
                            float v = gelu_f(acc[i][j][rr] + bv);
                            unsigned short ub = f2b_bits(v);
                            Cs[(i * 16 + q * 4 + rr) * 256 + wn * 64 + j * 16 + r] = *(__bf16*)&ub;
                        }
                }
            }
            __syncthreads();
            #pragma unroll
            for (int p = 0; p < 8; p++) {
                int idx = t + p * 512;
                int lrow = idx >> 5, ch = idx & 31;
                *(int4*)(Cg + ((size_t)(mb + hh * 128 + lrow) * N + nb) * 2 + ch * 16) =
                    *(const int4*)((const char*)Cs + lrow * 512 + ch * 16);
            }
            __syncthreads();
        }
    } else {   // EPI == 3: qkv scatter
        #pragma unroll
        for (int j = 0; j < 4; j++) {
            int n = nb + wn * 64 + j * 16 + r;
            float bv = bias[n];
            int sect = n >> 10, h = (n >> 6) & 15, e = n & 63;
            #pragma unroll
            for (int i = 0; i < 8; i++) {
                int mbase = mb + wm * 128 + i * 16 + q * 4;
                #pragma unroll
                for (int rr = 0; rr < 4; rr++) {
                    int m = mbase + rr;
                    int bi = m >> 9, s = m & 511;
                    size_t bh = (size_t)bi * NHEAD + h;
                    bf16 val = f2b(acc[i][j][rr] + bv);
                    if (sect == 0)      qb[((bh * SEQ + s) << 6) + e] = val;
                    else if (sect == 1) ktb[((bh * SEQ + s) << 6) + e] = val;  // K rows
                    else                vb[((bh * HDIM + e) << 9) + s] = val;  // V^T
                }
            }
        }
    }
}

// ---------------------------------------------------------------------------
// 2-phase 128x128 MFMA GEMM (proven): kept for N=1024 outputs (wo, w2) where
// a 256^2 grid would leave half the CUs idle. EPI 2: bias + fp32 residual.
// ---------------------------------------------------------------------------
template<int EPI, bool OUT_B16>
__global__ __launch_bounds__(256)
void gemm_bt(const bf16* __restrict__ A, const bf16* __restrict__ Bw,
             const float* __restrict__ bias, const float* __restrict__ resid,
             void* __restrict__ Cout, int M, int N, int K)
{
    int t    = threadIdx.x;
    int lane = t & 63, w = t >> 6;
    int wm   = w & 1,  wn = w >> 1;
    int q    = lane >> 4, r = lane & 15;

    int gx  = gridDim.x;
    int L   = blockIdx.y * gx + blockIdx.x;
    int qq  = (gx * gridDim.y) >> 3;
    int nid = (L & 7) * qq + (L >> 3);
    int mb  = (nid / gx) * 128, nb = (nid % gx) * 128;

    __shared__ char smem[32768];

    f32x4 acc[4][4] = {};

    const char* Ag = (const char*)((const unsigned short*)A + (size_t)mb * K);
    const char* Bg = (const char*)((const unsigned short*)Bw + (size_t)nb * K);

    int ar0 = t >> 2,  ac0 = (t & 3) << 3;

    int nt = K >> 5;

    #define STAGE(c, k0) do {                                      \
        char* dA = smem + (c) * 16384;                             \
        char* dB = dA + 8192;                                      \
        size_t off0 = ((size_t)ar0 * K + (k0) + ac0) * 2;          \
        size_t off1 = off0 + (size_t)64 * K * 2;                   \
        gll16(dA + t * 16,        Ag + off0);                      \
        gll16(dA + 4096 + t * 16, Ag + off1);                      \
        gll16(dB + t * 16,        Bg + off0);                      \
        gll16(dB + 4096 + t * 16, Bg + off1);                      \
    } while (0)

    STAGE(0, 0);
    __syncthreads();

    int cur = 0;
    for (int tt = 0; tt < nt; ++tt) {
        if (tt + 1 < nt) STAGE(cur ^ 1, (tt + 1) << 5);

        const __bf16* Asb = (const __bf16*)(smem + cur * 16384);
        const __bf16* Bsb = Asb + 4096;
        bf16x8 af[4], bfr[4];
        #pragma unroll
        for (int i = 0; i < 4; i++)
            af[i] = *(const bf16x8*)(Asb + (wm * 64 + i * 16 + r) * 32 + q * 8);
        #pragma unroll
        for (int j = 0; j < 4; j++)
            bfr[j] = *(const bf16x8*)(Bsb + (wn * 64 + j * 16 + r) * 32 + q * 8);
        #pragma unroll
        for (int i = 0; i < 4; i++)
            #pragma unroll
            for (int j = 0; j < 4; j++)
                acc[i][j] = __builtin_amdgcn_mfma_f32_16x16x32_bf16(af[i], bfr[j], acc[i][j], 0, 0, 0);

        __syncthreads();
        cur ^= 1;
    }
    #undef STAGE

    #pragma unroll
    for (int j = 0; j < 4; j++) {
        int n = nb + wn * 64 + j * 16 + r;
        float bv = bias[n];
        #pragma unroll
        for (int i = 0; i < 4; i++) {
            int mbase = mb + wm * 64 + i * 16 + q * 4;
            #pragma unroll
            for (int rr = 0; rr < 4; rr++) {
                int m = mbase + rr;
                float v = acc[i][j][rr] + bv;
                if (EPI == 1) v = gelu_f(v);
                if (EPI == 2) v += resid[(size_t)m * N + n];
                if (OUT_B16) ((bf16*)Cout)[(size_t)m * N + n] = f2b(v);
                else         ((float*)Cout)[(size_t)m * N + n] = v;
            }
        }
    }
}

// ---------------------------------------------------------------------------
// MFMA attention, LDS-pipelined (R8-verified). Grid (8,256) XCD-swizzled;
// keys in 8 chunks of 64, DMA-staged double-buffered K/V^T tiles, both-sides
// swizzle, one-pass no-max softmax, wave-private swizzled P tile.
// ---------------------------------------------------------------------------
__global__ __launch_bounds__(256, 3)
void attn_mfma(const bf16* __restrict__ Q, const bf16* __restrict__ K,
               const bf16* __restrict__ VT, const float* __restrict__ relb,
               bf16* __restrict__ out)
{
    int L   = blockIdx.x + (blockIdx.y << 3);   // grid (8,256) -> L in [0,2048)
    int xcd = L & 7, jj = L >> 3;
    int bh  = xcd * 32 + (jj >> 3);
    int q0  = (jj & 7) * 64;
    int b   = bh >> 4, h = bh & 15;
    int t = threadIdx.x, lane = t & 63, w = t >> 6;
    int l15 = lane & 15, l4 = lane >> 4;

    __shared__ int4  kvbuf4[2048];   // 32 KiB: 2 x (K-chunk 8KB + V-chunk 8KB)
    __shared__ int4  Pls4[512];      //  8 KiB P-tile [64 q][64 k], swizzled
    __shared__ float rbs[1024];      //  4 KiB rel-bias row for this head

    char* kv = (char*)kvbuf4;
    char* Pb = (char*)Pls4;
    const char* Kg = (const char*)K  + ((size_t)bh << 16);
    const char* Vg = (const char*)VT + ((size_t)bh << 16);

    #define STAGE_KV(bs, c) do {                                              \
        char* kd = kv + (bs) * 16384;                                         \
        char* vd = kd + 8192;                                                 \
        _Pragma("unroll")                                                     \
        for (int i = 0; i < 2; i++) {                                         \
            int g = t + i * 256;                                              \
            int rr_ = g >> 3;                                                 \
            int jj_ = (g & 7) ^ (rr_ & 7);                                    \
            gll16(kd + g * 16,                                                \
                  Kg + (((size_t)(c) * 64 + rr_) << 7) + (jj_ << 4));         \
            gll16(vd + g * 16,                                                \
                  Vg + ((size_t)rr_ << 10) + ((size_t)(c) << 7) + (jj_ << 4));\
        }                                                                     \
    } while (0)

    const float* rb = relb + (size_t)h * (2 * SEQ - 1);
    for (int i = t; i < 2 * SEQ - 1; i += 256) rbs[i] = rb[i];
    STAGE_KV(0, 0);

    const unsigned short* Qp = (const unsigned short*)Q
        + (((size_t)bh * SEQ + q0 + w * 16 + l15) << 6) + l4 * 8;
    bf16x8 qf0 = *(const bf16x8*)Qp;
    bf16x8 qf1 = *(const bf16x8*)(Qp + 32);

    __syncthreads();   // stage 0 + rbs visible

    int qbase  = q0 + w * 16 + l4 * 4;
    int prow   = w * 16 + l15;
    int prbase = prow << 7;
    int pswz   = (prow & 7) << 4;
    float sum[4] = {0.f, 0.f, 0.f, 0.f};
    f32x4 oacc[4] = {};

    int cur = 0;
    for (int c = 0; c < 8; ++c) {
        if (c < 7) STAGE_KV(cur ^ 1, c + 1);

        const char* Kl = kv + cur * 16384;
        const char* Vl = Kl + 8192;

        f32x4 sc[4];
        #pragma unroll
        for (int kt = 0; kt < 4; kt++) {
            int row = kt * 16 + l15;
            int swz = (row & 7) << 4;
            bf16x8 kf0 = *(const bf16x8*)(Kl + (((row << 7) + (l4 << 4)) ^ swz));
            bf16x8 kf1 = *(const bf16x8*)(Kl + (((row << 7) + 64 + (l4 << 4)) ^ swz));
            f32x4 a = {};
            a = __builtin_amdgcn_mfma_f32_16x16x32_bf16(qf0, kf0, a, 0, 0, 0);
            a = __builtin_amdgcn_mfma_f32_16x16x32_bf16(qf1, kf1, a, 0, 0, 0);
            sc[kt] = a;
        }

        #pragma unroll
        for (int kt = 0; kt < 4; kt++) {
            int relbase = qbase - (c * 64 + kt * 16 + l15) + (SEQ - 1);
            #pragma unroll
            for (int reg = 0; reg < 4; reg++) {
                float p = __expf(sc[kt][reg] * 0.125f + rbs[relbase + reg]);
                sum[reg] += p;
                float o = __shfl_xor(p, 1, 64);
                unsigned lo = f2b_bits((lane & 1) ? o : p);
                unsigned hi = f2b_bits((lane & 1) ? p : o);
                unsigned pk = lo | (hi << 16);
                if ((lane & 1) == (reg >> 1)) {
                    int row  = w * 16 + l4 * 4 + reg;
                    int byte = ((row << 7) + (kt << 5) + ((l15 & ~1) << 1))
                             ^ ((row & 7) << 4);
                    *(unsigned*)(Pb + byte) = pk;
                }
            }
        }

        #pragma unroll
        for (int k2 = 0; k2 < 2; k2++) {
            int pbyte = (prbase + (k2 << 6) + (l4 << 4)) ^ pswz;
            bf16x8 pf = *(const bf16x8*)(Pb + pbyte);
            #pragma unroll
            for (int et = 0; et < 4; et++) {
                int vrow = et * 16 + l15;
                bf16x8 vf = *(const bf16x8*)
                    (Vl + (((vrow << 7) + (k2 << 6) + (l4 << 4)) ^ ((vrow & 7) << 4)));
                oacc[et] = __builtin_amdgcn_mfma_f32_16x16x32_bf16(pf, vf, oacc[et], 0, 0, 0);
            }
        }

        __syncthreads();
        cur ^= 1;
    }
    #undef STAGE_KV

    #pragma unroll
    for (int m = 1; m < 16; m <<= 1)
        #pragma unroll
        for (int reg = 0; reg < 4; reg++)
            sum[reg] += __shfl_xor(sum[reg], m, 64);
    float rcp[4];
    #pragma unroll
    for (int reg = 0; reg < 4; reg++) rcp[reg] = 1.0f / sum[reg];

    bf16* op = out + (size_t)(b * SEQ + q0 + w * 16 + l4 * 4) * D_MODEL
             + h * HDIM + l15;
    #pragma unroll
    for (int et = 0; et < 4; et++)
        #pragma unroll
        for (int reg = 0; reg < 4; reg++)
            op[(size_t)reg * D_MODEL + et * 16] = f2b(oacc[et][reg] * rcp[reg]);
}

// ---------------------------------------------------------------------------
// Launch. Inputs fp32 (dict order), OUTPUT fp32 (reference dtype).
// ws peak 121 MiB:
//   [1,7)   wqkv_b  [7,9) wo_b     (live through step 5)
//   [1,9)   w1_b    (cvt after Wo gemm)    [9,17) w2_b (cvt after w1 gemm)
//   [9,25)  xn -> xn2
//   [25,41) Q  [41,57) K  -> x1 fp32 [25,57) after attention
//   [57,121) hid bf16 8192x4096
// d_out scratch: VT bf16 [0,16M), att bf16 [16M,32M).
// ---------------------------------------------------------------------------
extern "C" void kernel_launch(void* const* d_in, const int* in_sizes, int n_in,
                              void* d_out, int out_size, void* d_ws, size_t ws_size,
                              hipStream_t stream)
{
    const float* x    = (const float*)d_in[0];
    const float* wqkv = (const float*)d_in[1];
    const float* bqkv = (const float*)d_in[2];
    const float* wo   = (const float*)d_in[3];
    const float* bo   = (const float*)d_in[4];
    const float* relb = (const float*)d_in[5];
    const float* w1   = (const float*)d_in[6];
    const float* b1   = (const float*)d_in[7];
    const float* w2   = (const float*)d_in[8];
    const float* b2   = (const float*)d_in[9];
    const float* ln1w = (const float*)d_in[10];
    const float* ln1b = (const float*)d_in[11];
    const float* ln2w = (const float*)d_in[12];
    const float* ln2b = (const float*)d_in[13];

    char* ws = (char*)d_ws;
    const size_t MB = 1048576;
    bf16*  wqkv_b = (bf16*)(ws + 1 * MB);
    bf16*  wo_b   = (bf16*)(ws + 7 * MB);
    bf16*  xn     = (bf16*)(ws + 9 * MB);
    bf16*  Qb     = (bf16*)(ws + 25 * MB);
    bf16*  Kb     = (bf16*)(ws + 41 * MB);
    float* x1     = (float*)(ws + 25 * MB);  // over dead Q+K, 32 MiB
    bf16*  w1_b   = (bf16*)(ws + 1 * MB);    // over dead wqkv_b+wo_b (step 6)
    bf16*  w2_b   = (bf16*)(ws + 9 * MB);    // over dead xn2 (step 9)
    bf16*  xn2    = (bf16*)(ws + 9 * MB);    // over dead xn
    bf16*  hid    = (bf16*)(ws + 57 * MB);   // 8192x4096 bf16, 64 MiB
    bf16*  VT     = (bf16*)d_out;                       // d_out[0,16M)
    bf16*  att    = (bf16*)((char*)d_out + 16 * MB);    // d_out[16M,32M)
    float* out    = (float*)d_out;

    // 1. attention-path weights fp32 -> bf16
    cvt_kernel<<<3072, 256, 0, stream>>>(wqkv, wqkv_b, 3 * D_MODEL * D_MODEL);
    cvt_kernel<<<1024, 256, 0, stream>>>(wo,   wo_b,   D_MODEL * D_MODEL);
    // 2. xn = LN1(x)
    ln_kernel<<<MROWS, 256, 0, stream>>>(x, ln1w, ln1b, xn);
    // 3. qkv projection (256^2 8-phase) scattered into Q / K / VT
    gemm8<3><<<dim3(12, 32), 512, 0, stream>>>(xn, wqkv_b, bqkv, nullptr,
        Qb, Kb, VT, MROWS, 3 * D_MODEL, D_MODEL);
    // 4. MFMA attention -> att (d_out scratch, bf16)
    attn_mfma<<<dim3(8, 256), 256, 0, stream>>>(Qb, Kb, VT, relb, att);
    // 5. x1 = x + att @ Wo^T + bo   (fp32, over dead Q+K)
    gemm_bt<2,false><<<dim3(8, 64), 256, 0, stream>>>(att, wo_b, bo, x,
        x1, MROWS, D_MODEL, D_MODEL);
    // 6. w1 -> bf16 (over dead wqkv_b+wo_b)
    cvt_kernel<<<4096, 256, 0, stream>>>(w1, w1_b, DFF * D_MODEL);
    // 7. xn2 = LN2(x1)   (over dead xn)
    ln_kernel<<<MROWS, 256, 0, stream>>>(x1, ln2w, ln2b, xn2);
    // 8. hid = GELU(xn2 @ w1^T + b1), 256^2 8-phase, 512 blocks
    gemm8<1><<<dim3(16, 32), 512, 0, stream>>>(xn2, w1_b, b1, hid,
        nullptr, nullptr, nullptr, MROWS, DFF, D_MODEL);
    // 9. w2 -> bf16 (over dead xn2)
    cvt_kernel<<<4096, 256, 0, stream>>>(w2, w2_b, D_MODEL * DFF);
    // 10. out = x1 + hid @ w2^T + b2, fp32 into d_out
    gemm_bt<2,false><<<dim3(8, 64), 256, 0, stream>>>(hid, w2_b, b2, x1,
        out, MROWS, D_MODEL, DFF);
}

// Round 10
// 595.530 us; speedup vs baseline: 1.1156x; 1.1156x over previous
//
#include <hip/hip_runtime.h>
#include <hip/hip_bf16.h>
#include <stdint.h>

typedef __hip_bfloat16 bf16;
typedef __attribute__((ext_vector_type(8))) __bf16 bf16x8;
typedef __attribute__((ext_vector_type(4))) float f32x4;

#define D_MODEL 1024
#define NHEAD   16
#define HDIM    64
#define DFF     4096
#define BATCH   16
#define SEQ     512
#define MROWS   (BATCH*SEQ)   // 8192

__device__ __forceinline__ float b2f_bits(unsigned short u) {
    return __uint_as_float(((unsigned)u) << 16);
}
__device__ __forceinline__ bf16 f2b(float v) { return __float2bfloat16(v); }
__device__ __forceinline__ unsigned short f2b_bits(float v) {
    bf16 t = __float2bfloat16(v);
    return *(unsigned short*)&t;
}
// async global->LDS, 16B per lane (dest = wave-uniform base + lane*16)
__device__ __forceinline__ void gll16(void* lds, const void* gsrc) {
    __builtin_amdgcn_global_load_lds(
        (const __attribute__((address_space(1))) unsigned*)gsrc,
        (__attribute__((address_space(3))) unsigned*)lds,
        16, 0, 0);
}
// exact-enough GELU: tanh form, max |err| ~3e-4 vs erf form (ok at bf16 out)
__device__ __forceinline__ float gelu_f(float u) {
    float z  = 0.7978845608028654f * (u + 0.044715f * u * u * u);
    float az = fabsf(z);
    float e  = __expf(-2.0f * az);
    float th = (1.0f - e) / (1.0f + e);
    th = copysignf(th, z);
    return 0.5f * u * (1.0f + th);
}

// ---------------------------------------------------------------------------
// fp32 -> bf16 weight conversion (n multiple of 4; grid covers exactly n/4)
// ---------------------------------------------------------------------------
__global__ __launch_bounds__(256)
void cvt_kernel(const float* __restrict__ in, bf16* __restrict__ out, int n)
{
    int i = (blockIdx.x * 256 + threadIdx.x) * 4;
    if (i >= n) return;
    float4 f = *(const float4*)(in + i);
    ushort4 o;
    o.x = f2b_bits(f.x); o.y = f2b_bits(f.y);
    o.z = f2b_bits(f.z); o.w = f2b_bits(f.w);
    *(ushort4*)((unsigned short*)out + i) = o;
}

// ---------------------------------------------------------------------------
// LayerNorm: fp32 in, bf16 out. One block (256 threads) per row of 1024.
// ---------------------------------------------------------------------------
__global__ __launch_bounds__(256)
void ln_kernel(const float* __restrict__ xin, const float* __restrict__ w,
               const float* __restrict__ b, bf16* __restrict__ out)
{
    int row  = blockIdx.x;
    int t    = threadIdx.x;
    int lane = t & 63, wv = t >> 6;
    int col  = t * 4;

    float4 f = *(const float4*)(xin + (size_t)row * D_MODEL + col);
    float v[4] = {f.x, f.y, f.z, f.w};

    float s  = v[0] + v[1] + v[2] + v[3];
    float ss = v[0]*v[0] + v[1]*v[1] + v[2]*v[2] + v[3]*v[3];
    #pragma unroll
    for (int m = 1; m < 64; m <<= 1) {
        s  += __shfl_xor(s,  m, 64);
        ss += __shfl_xor(ss, m, 64);
    }
    __shared__ float rs0[4], rs1[4];
    if (lane == 0) { rs0[wv] = s; rs1[wv] = ss; }
    __syncthreads();
    s  = rs0[0] + rs0[1] + rs0[2] + rs0[3];
    ss = rs1[0] + rs1[1] + rs1[2] + rs1[3];

    float mu  = s * (1.0f / D_MODEL);
    float var = ss * (1.0f / D_MODEL) - mu * mu;
    float rs  = rsqrtf(var + 1e-5f);

    float4 wf = *(const float4*)(w + col);
    float4 bf = *(const float4*)(b + col);
    ushort4 o;
    o.x = f2b_bits((v[0]-mu)*rs*wf.x + bf.x);
    o.y = f2b_bits((v[1]-mu)*rs*wf.y + bf.y);
    o.z = f2b_bits((v[2]-mu)*rs*wf.z + bf.z);
    o.w = f2b_bits((v[3]-mu)*rs*wf.w + bf.w);
    *(ushort4*)((unsigned short*)out + (size_t)row * D_MODEL + col) = o;
}

// ---------------------------------------------------------------------------
// MFMA GEMM (R8-proven 2-phase): C[M,N] = A[M,K]*Bw[N,K]^T + bias. Epilogues:
//   EPI 0: bias   EPI 1: bias + fast GELU   EPI 2: bias + fp32 residual
//   EPI 3: bias -> scatter bf16 Q (b,h,s,e) / K (b,h,s,e) / VT (b,h,e,s)
// 128x128 tile, 256 thr (4 waves 2x2), wave = 4x4 mfma_f32_16x16x32_bf16.
// Double-buffered 2x16KB LDS via global_load_lds; one barrier per K-step.
// bf16 C-path stages C-tile through LDS, copies out 16B/lane full rows.
// XCD-aware block remap (T1): nwg%8==0 -> bijective chunked map.
// C/D mapping (m89/m91 verified): col = lane&15, row = (lane>>4)*4 + reg.
// NOTE (R9 lesson): the 256^2 8-phase/counted-vmcnt port regressed (1 blk/CU
// + 2-half-deep pipeline exposes latency; m248 caps K=1024 gain at +10%).
// ---------------------------------------------------------------------------
template<int EPI, bool OUT_B16>
__global__ __launch_bounds__(256)
void gemm_bt(const bf16* __restrict__ A, const bf16* __restrict__ Bw,
             const float* __restrict__ bias, const float* __restrict__ resid,
             void* __restrict__ Cout, bf16* __restrict__ qb,
             bf16* __restrict__ ktb, bf16* __restrict__ vb,
             int M, int N, int K)
{
    int t    = threadIdx.x;
    int lane = t & 63, w = t >> 6;
    int wm   = w & 1,  wn = w >> 1;
    int q    = lane >> 4, r = lane & 15;

    // XCD swizzle: dispatch index L round-robins L&7 over XCDs (m09);
    // give each XCD a contiguous chunk of the original tile ordering.
    int gx  = gridDim.x;
    int L   = blockIdx.y * gx + blockIdx.x;
    int qq  = (gx * gridDim.y) >> 3;
    int nid = (L & 7) * qq + (L >> 3);
    int mb  = (nid / gx) * 128, nb = (nid % gx) * 128;

    // buf c: A at smem+c*16384 (8KB), B at +8192. C-stage reuses all 32KB.
    __shared__ char smem[32768];

    f32x4 acc[4][4] = {};

    const char* Ag = (const char*)((const unsigned short*)A + (size_t)mb * K);
    const char* Bg = (const char*)((const unsigned short*)Bw + (size_t)nb * K);

    int ar0 = t >> 2,  ac0 = (t & 3) << 3;   // row, elem-col of this thread's 16B

    int nt = K >> 5;

    #define STAGE(c, k0) do {                                      \
        char* dA = smem + (c) * 16384;                             \
        char* dB = dA + 8192;                                      \
        size_t off0 = ((size_t)ar0 * K + (k0) + ac0) * 2;          \
        size_t off1 = off0 + (size_t)64 * K * 2;                   \
        gll16(dA + t * 16,        Ag + off0);                      \
        gll16(dA + 4096 + t * 16, Ag + off1);                      \
        gll16(dB + t * 16,        Bg + off0);                      \
        gll16(dB + 4096 + t * 16, Bg + off1);                      \
    } while (0)

    STAGE(0, 0);
    __syncthreads();

    int cur = 0;
    for (int tt = 0; tt < nt; ++tt) {
        if (tt + 1 < nt) STAGE(cur ^ 1, (tt + 1) << 5);   // prefetch next tile

        const __bf16* Asb = (const __bf16*)(smem + cur * 16384);
        const __bf16* Bsb = Asb + 4096;
        bf16x8 af[4], bfr[4];
        #pragma unroll
        for (int i = 0; i < 4; i++)
            af[i] = *(const bf16x8*)(Asb + (wm * 64 + i * 16 + r) * 32 + q * 8);
        #pragma unroll
        for (int j = 0; j < 4; j++)
            bfr[j] = *(const bf16x8*)(Bsb + (wn * 64 + j * 16 + r) * 32 + q * 8);
        #pragma unroll
        for (int i = 0; i < 4; i++)
            #pragma unroll
            for (int j = 0; j < 4; j++)
                acc[i][j] = __builtin_amdgcn_mfma_f32_16x16x32_bf16(af[i], bfr[j], acc[i][j], 0, 0, 0);

        __syncthreads();   // drains vmcnt (next tile ready) + lgkm (reads done)
        cur ^= 1;
    }
    #undef STAGE

    if (OUT_B16 && EPI != 3) {
        // stage C-tile bf16 in LDS, copy out coalesced (256B rows, 16B/lane)
        __bf16* Cs = (__bf16*)smem;
        #pragma unroll
        for (int j = 0; j < 4; j++) {
            int n = nb + wn * 64 + j * 16 + r;
            float bv = bias[n];
            #pragma unroll
            for (int i = 0; i < 4; i++) {
                #pragma unroll
                for (int rr = 0; rr < 4; rr++) {
                    float v = acc[i][j][rr] + bv;
                    if (EPI == 1) v = gelu_f(v);
                    if (EPI == 2) v += resid[(size_t)(mb + wm*64 + i*16 + q*4 + rr) * N + n];
                    unsigned short ub = f2b_bits(v);
                    Cs[(wm*64 + i*16 + q*4 + rr) * 128 + wn*64 + j*16 + r] = *(__bf16*)&ub;
                }
            }
        }
        __syncthreads();
        char* Cg = (char*)Cout;
        #pragma unroll
        for (int c = 0; c < 8; c++) {
            int idx = t + c * 256;           // 2048 chunks: row = idx>>4, 16B ch
            int row = idx >> 4, ch = idx & 15;
            *(int4*)(Cg + ((size_t)(mb + row) * N + nb) * 2 + ch * 16) =
                *(const int4*)((const char*)Cs + row * 256 + ch * 16);
        }
    } else {
        #pragma unroll
        for (int j = 0; j < 4; j++) {
            int n = nb + wn * 64 + j * 16 + r;
            float bv = bias[n];
            #pragma unroll
            for (int i = 0; i < 4; i++) {
                int mbase = mb + wm * 64 + i * 16 + q * 4;
                #pragma unroll
                for (int rr = 0; rr < 4; rr++) {
                    int m = mbase + rr;
                    float v = acc[i][j][rr] + bv;
                    if (EPI == 1) v = gelu_f(v);
                    if (EPI == 2) v += resid[(size_t)m * N + n];
                    if (EPI == 3) {
                        int sect = n >> 10;
                        int h = (n >> 6) & 15;
                        int e = n & 63;
                        int bi = m >> 9, s = m & 511;
                        size_t bh = (size_t)bi * NHEAD + h;
                        bf16 val = f2b(v);
                        if (sect == 0)      qb[((bh * SEQ + s) << 6) + e] = val;
                        else if (sect == 1) ktb[((bh * SEQ + s) << 6) + e] = val;  // K rows
                        else                vb[((bh * HDIM + e) << 9) + s] = val;  // V^T
                    } else {
                        if (OUT_B16) ((bf16*)Cout)[(size_t)m * N + n] = f2b(v);
                        else         ((float*)Cout)[(size_t)m * N + n] = v;
                    }
                }
            }
        }
    }
}

// ---------------------------------------------------------------------------
// MFMA attention, LDS-pipelined, 128 q-rows per block. Grid (4,256)
// XCD-swizzled: xcd = L&7 owns bh in [xcd*32,+32), q-tile fastest.
// 256 thr = 4 waves; wave = 2 sequential halves of 16 q-rows (h=0,1 reuse
// sc regs + P-LDS rows within the wave -> only +~30 VGPR vs R8).
// Keys in 8 chunks of 64, double-buffered DMA K/V^T staging (zero data
// VGPRs), one barrier per chunk. Doubling compute per chunk (~1000cy) fully
// covers the staged-DMA latency that R8's 64-row version half-exposed, and
// halves per-bh staging redundancy (4 blocks/bh instead of 8).
// Bank conflicts: both-sides involution (rule #21): linear DMA dest +
// pre-swizzled global source (granule j ^= row&7) + swizzled ds_read
// (byte ^= (row&7)<<4). One-pass no-max softmax (|s| <~ 10 << 88).
// LDS 44KB -> 3 blocks/CU; launch_bounds(256,3): VGPR cap 170, demand ~130.
// C/D: col=lane&15, row=(lane>>4)*4+reg (m89/m91 verified).
// ---------------------------------------------------------------------------
__global__ __launch_bounds__(256, 3)
void attn_mfma(const bf16* __restrict__ Q, const bf16* __restrict__ K,
               const bf16* __restrict__ VT, const float* __restrict__ relb,
               bf16* __restrict__ out)
{
    int L   = blockIdx.x + (blockIdx.y << 2);   // grid (4,256) -> L in [0,1024)
    int xcd = L & 7, jj = L >> 3;               // jj in [0,128)
    int bh  = xcd * 32 + (jj >> 2);
    int q0  = (jj & 3) * 128;
    int b   = bh >> 4, hd = bh & 15;
    int t = threadIdx.x, lane = t & 63, w = t >> 6;
    int l15 = lane & 15, l4 = lane >> 4;

    __shared__ int4  kvbuf4[2048];   // 32 KiB: 2 x (K-chunk 8KB + V-chunk 8KB)
    __shared__ int4  Pls4[512];      //  8 KiB P-tile [64 q][64 k], swizzled
    __shared__ float rbs[1024];      //  4 KiB rel-bias row for this head

    char* kv = (char*)kvbuf4;
    char* Pb = (char*)Pls4;
    const char* Kg = (const char*)K  + ((size_t)bh << 16);
    const char* Vg = (const char*)VT + ((size_t)bh << 16);

    #define STAGE_KV(bs, c) do {                                              \
        char* kd = kv + (bs) * 16384;                                         \
        char* vd = kd + 8192;                                                 \
        _Pragma("unroll")                                                     \
        for (int i = 0; i < 2; i++) {                                         \
            int g = t + i * 256;                                              \
            int rr_ = g >> 3;                                                 \
            int jj_ = (g & 7) ^ (rr_ & 7);                                    \
            gll16(kd + g * 16,                                                \
                  Kg + (((size_t)(c) * 64 + rr_) << 7) + (jj_ << 4));         \
            gll16(vd + g * 16,                                                \
                  Vg + ((size_t)rr_ << 10) + ((size_t)(c) << 7) + (jj_ << 4));\
        }                                                                     \
    } while (0)

    const float* rb = relb + (size_t)hd * (2 * SEQ - 1);
    for (int i = t; i < 2 * SEQ - 1; i += 256) rbs[i] = rb[i];
    STAGE_KV(0, 0);

    // Q fragments for both 64-row halves (loaded while stage 0 in flight)
    bf16x8 qf[2][2];
    #pragma unroll
    for (int h = 0; h < 2; h++) {
        const unsigned short* Qp = (const unsigned short*)Q
            + (((size_t)bh * SEQ + q0 + h * 64 + w * 16 + l15) << 6) + l4 * 8;
        qf[h][0] = *(const bf16x8*)Qp;
        qf[h][1] = *(const bf16x8*)(Qp + 32);
    }

    __syncthreads();   // stage 0 + rbs visible

    int prow   = w * 16 + l15;                 // PV A-frag read row
    int prbase = prow << 7;                    // 128 B row stride
    int pswz   = (prow & 7) << 4;
    float sum[2][4] = {};
    f32x4 oacc[2][4] = {};

    int cur = 0;
    for (int c = 0; c < 8; ++c) {
        if (c < 7) STAGE_KV(cur ^ 1, c + 1);   // DMA next chunk (no VGPRs)

        const char* Kl = kv + cur * 16384;
        const char* Vl = Kl + 8192;

        #pragma unroll
        for (int h = 0; h < 2; h++) {
            // ---- QK^T: 4 key-tiles of 16, 2 MFMAs each (K=64) ----
            f32x4 sc[4];
            #pragma unroll
            for (int kt = 0; kt < 4; kt++) {
                int row = kt * 16 + l15;
                int swz = (row & 7) << 4;
                bf16x8 kf0 = *(const bf16x8*)(Kl + (((row << 7) + (l4 << 4)) ^ swz));
                bf16x8 kf1 = *(const bf16x8*)(Kl + (((row << 7) + 64 + (l4 << 4)) ^ swz));
                f32x4 a = {};
                a = __builtin_amdgcn_mfma_f32_16x16x32_bf16(qf[h][0], kf0, a, 0, 0, 0);
                a = __builtin_amdgcn_mfma_f32_16x16x32_bf16(qf[h][1], kf1, a, 0, 0, 0);
                sc[kt] = a;
            }

            // ---- bias + exp + sum + pack -> swizzled P (wave-private rows) ----
            int qbase = q0 + h * 64 + w * 16 + l4 * 4;
            #pragma unroll
            for (int kt = 0; kt < 4; kt++) {
                int relbase = qbase - (c * 64 + kt * 16 + l15) + (SEQ - 1);
                #pragma unroll
                for (int reg = 0; reg < 4; reg++) {
                    float p = __expf(sc[kt][reg] * 0.125f + rbs[relbase + reg]);
                    sum[h][reg] += p;
                    float o = __shfl_xor(p, 1, 64);
                    unsigned lo = f2b_bits((lane & 1) ? o : p);
                    unsigned hi = f2b_bits((lane & 1) ? p : o);
                    unsigned pk = lo | (hi << 16);
                    if ((lane & 1) == (reg >> 1)) {      // even lanes: reg 0,1; odd: 2,3
                        int row  = w * 16 + l4 * 4 + reg;
                        int byte = ((row << 7) + (kt << 5) + ((l15 & ~1) << 1))
                                 ^ ((row & 7) << 4);
                        *(unsigned*)(Pb + byte) = pk;
                    }
                }
            }

            // ---- PV: 2 k-slices of 32 keys x 4 e-tiles ----
            // (same-wave program order: h=1's pack can't pass h=0's reads)
            #pragma unroll
            for (int k2 = 0; k2 < 2; k2++) {
                int pbyte = (prbase + (k2 << 6) + (l4 << 4)) ^ pswz;
                bf16x8 pf = *(const bf16x8*)(Pb + pbyte);
                #pragma unroll
                for (int et = 0; et < 4; et++) {
                    int vrow = et * 16 + l15;
                    bf16x8 vf = *(const bf16x8*)
                        (Vl + (((vrow << 7) + (k2 << 6) + (l4 << 4)) ^ ((vrow & 7) << 4)));
                    oacc[h][et] = __builtin_amdgcn_mfma_f32_16x16x32_bf16(pf, vf, oacc[h][et], 0, 0, 0);
                }
            }
        }

        __syncthreads();   // stage c+1 landed; all waves done reading buf cur
        cur ^= 1;
    }
    #undef STAGE_KV

    #pragma unroll
    for (int h = 0; h < 2; h++) {
        #pragma unroll
        for (int m = 1; m < 16; m <<= 1)
            #pragma unroll
            for (int reg = 0; reg < 4; reg++)
                sum[h][reg] += __shfl_xor(sum[h][reg], m, 64);
        float rcp[4];
        #pragma unroll
        for (int reg = 0; reg < 4; reg++) rcp[reg] = 1.0f / sum[h][reg];

        bf16* op = out + (size_t)(b * SEQ + q0 + h * 64 + w * 16 + l4 * 4) * D_MODEL
                 + hd * HDIM + l15;
        #pragma unroll
        for (int et = 0; et < 4; et++)
            #pragma unroll
            for (int reg = 0; reg < 4; reg++)
                op[(size_t)reg * D_MODEL + et * 16] = f2b(oacc[h][et][reg] * rcp[reg]);
    }
}

// ---------------------------------------------------------------------------
// Launch. Inputs fp32 (dict order), OUTPUT fp32 (reference dtype).
// ws peak 121 MiB:
//   [1,7)   wqkv_b  [7,9) wo_b     (live through step 5)
//   [1,9)   w1_b    (cvt after Wo gemm)    [9,17) w2_b (cvt after w1 gemm)
//   [9,25)  xn -> xn2
//   [25,41) Q  [41,57) K  -> x1 fp32 [25,57) after attention
//   [57,121) hid bf16 8192x4096
// d_out scratch: VT bf16 [0,16M), att bf16 [16M,32M).
// ---------------------------------------------------------------------------
extern "C" void kernel_launch(void* const* d_in, const int* in_sizes, int n_in,
                              void* d_out, int out_size, void* d_ws, size_t ws_size,
                              hipStream_t stream)
{
    const float* x    = (const float*)d_in[0];
    const float* wqkv = (const float*)d_in[1];
    const float* bqkv = (const float*)d_in[2];
    const float* wo   = (const float*)d_in[3];
    const float* bo   = (const float*)d_in[4];
    const float* relb = (const float*)d_in[5];
    const float* w1   = (const float*)d_in[6];
    const float* b1   = (const float*)d_in[7];
    const float* w2   = (const float*)d_in[8];
    const float* b2   = (const float*)d_in[9];
    const float* ln1w = (const float*)d_in[10];
    const float* ln1b = (const float*)d_in[11];
    const float* ln2w = (const float*)d_in[12];
    const float* ln2b = (const float*)d_in[13];

    char* ws = (char*)d_ws;
    const size_t MB = 1048576;
    bf16*  wqkv_b = (bf16*)(ws + 1 * MB);
    bf16*  wo_b   = (bf16*)(ws + 7 * MB);
    bf16*  xn     = (bf16*)(ws + 9 * MB);
    bf16*  Qb     = (bf16*)(ws + 25 * MB);
    bf16*  Kb     = (bf16*)(ws + 41 * MB);
    float* x1     = (float*)(ws + 25 * MB);  // over dead Q+K, 32 MiB
    bf16*  w1_b   = (bf16*)(ws + 1 * MB);    // over dead wqkv_b+wo_b (step 6)
    bf16*  w2_b   = (bf16*)(ws + 9 * MB);    // over dead xn2 (step 9)
    bf16*  xn2    = (bf16*)(ws + 9 * MB);    // over dead xn
    bf16*  hid    = (bf16*)(ws + 57 * MB);   // 8192x4096 bf16, 64 MiB
    bf16*  VT     = (bf16*)d_out;                       // d_out[0,16M)
    bf16*  att    = (bf16*)((char*)d_out + 16 * MB);    // d_out[16M,32M)
    float* out    = (float*)d_out;

    // 1. attention-path weights fp32 -> bf16
    cvt_kernel<<<3072, 256, 0, stream>>>(wqkv, wqkv_b, 3 * D_MODEL * D_MODEL);
    cvt_kernel<<<1024, 256, 0, stream>>>(wo,   wo_b,   D_MODEL * D_MODEL);
    // 2. xn = LN1(x)
    ln_kernel<<<MROWS, 256, 0, stream>>>(x, ln1w, ln1b, xn);
    // 3. qkv projection scattered into Q / K / VT(=d_out scratch)
    gemm_bt<3,true><<<dim3(24, 64), 256, 0, stream>>>(xn, wqkv_b, bqkv, nullptr,
        nullptr, Qb, Kb, VT, MROWS, 3 * D_MODEL, D_MODEL);
    // 4. MFMA attention (128 q-rows/block) -> att (d_out scratch, bf16)
    attn_mfma<<<dim3(4, 256), 256, 0, stream>>>(Qb, Kb, VT, relb, att);
    // 5. x1 = x + att @ Wo^T + bo   (fp32, over dead Q+K)
    gemm_bt<2,false><<<dim3(8, 64), 256, 0, stream>>>(att, wo_b, bo, x,
        x1, nullptr, nullptr, nullptr, MROWS, D_MODEL, D_MODEL);
    // 6. w1 -> bf16 (over dead wqkv_b+wo_b)
    cvt_kernel<<<4096, 256, 0, stream>>>(w1, w1_b, DFF * D_MODEL);
    // 7. xn2 = LN2(x1)   (over dead xn)
    ln_kernel<<<MROWS, 256, 0, stream>>>(x1, ln2w, ln2b, xn2);
    // 8. hid = GELU(xn2 @ w1^T + b1), full M: 2048 blocks
    gemm_bt<1,true><<<dim3(32, 64), 256, 0, stream>>>(xn2, w1_b, b1, nullptr,
        hid, nullptr, nullptr, nullptr, MROWS, DFF, D_MODEL);
    // 9. w2 -> bf16 (over dead xn2)
    cvt_kernel<<<4096, 256, 0, stream>>>(w2, w2_b, D_MODEL * DFF);
    // 10. out = x1 + hid @ w2^T + b2, full M: 512 blocks, fp32 into d_out
    gemm_bt<2,false><<<dim3(8, 64), 256, 0, stream>>>(hid, w2_b, b2, x1,
        out, nullptr, nullptr, nullptr, MROWS, D_MODEL, DFF);
}

// Round 11
// 532.221 us; speedup vs baseline: 1.2484x; 1.1190x over previous
//
#include <hip/hip_runtime.h>
#include <hip/hip_bf16.h>
#include <stdint.h>

typedef __hip_bfloat16 bf16;
typedef __attribute__((ext_vector_type(8))) __bf16 bf16x8;
typedef __attribute__((ext_vector_type(4))) float f32x4;

#define D_MODEL 1024
#define NHEAD   16
#define HDIM    64
#define DFF     4096
#define BATCH   16
#define SEQ     512
#define MROWS   (BATCH*SEQ)   // 8192

__device__ __forceinline__ float b2f_bits(unsigned short u) {
    return __uint_as_float(((unsigned)u) << 16);
}
__device__ __forceinline__ bf16 f2b(float v) { return __float2bfloat16(v); }
__device__ __forceinline__ unsigned short f2b_bits(float v) {
    bf16 t = __float2bfloat16(v);
    return *(unsigned short*)&t;
}
// async global->LDS, 16B per lane (dest = wave-uniform base + lane*16)
__device__ __forceinline__ void gll16(void* lds, const void* gsrc) {
    __builtin_amdgcn_global_load_lds(
        (const __attribute__((address_space(1))) unsigned*)gsrc,
        (__attribute__((address_space(3))) unsigned*)lds,
        16, 0, 0);
}
// exact-enough GELU: tanh form, max |err| ~3e-4 vs erf form (ok at bf16 out)
__device__ __forceinline__ float gelu_f(float u) {
    float z  = 0.7978845608028654f * (u + 0.044715f * u * u * u);
    float az = fabsf(z);
    float e  = __expf(-2.0f * az);
    float th = (1.0f - e) / (1.0f + e);
    th = copysignf(th, z);
    return 0.5f * u * (1.0f + th);
}

// ---------------------------------------------------------------------------
// fp32 -> bf16 weight conversion (n multiple of 4; grid covers exactly n/4)
// ---------------------------------------------------------------------------
__global__ __launch_bounds__(256)
void cvt_kernel(const float* __restrict__ in, bf16* __restrict__ out, int n)
{
    int i = (blockIdx.x * 256 + threadIdx.x) * 4;
    if (i >= n) return;
    float4 f = *(const float4*)(in + i);
    ushort4 o;
    o.x = f2b_bits(f.x); o.y = f2b_bits(f.y);
    o.z = f2b_bits(f.z); o.w = f2b_bits(f.w);
    *(ushort4*)((unsigned short*)out + i) = o;
}

// ---------------------------------------------------------------------------
// LayerNorm: fp32 in, bf16 out. One block (256 threads) per row of 1024.
// ---------------------------------------------------------------------------
__global__ __launch_bounds__(256)
void ln_kernel(const float* __restrict__ xin, const float* __restrict__ w,
               const float* __restrict__ b, bf16* __restrict__ out)
{
    int row  = blockIdx.x;
    int t    = threadIdx.x;
    int lane = t & 63, wv = t >> 6;
    int col  = t * 4;

    float4 f = *(const float4*)(xin + (size_t)row * D_MODEL + col);
    float v[4] = {f.x, f.y, f.z, f.w};

    float s  = v[0] + v[1] + v[2] + v[3];
    float ss = v[0]*v[0] + v[1]*v[1] + v[2]*v[2] + v[3]*v[3];
    #pragma unroll
    for (int m = 1; m < 64; m <<= 1) {
        s  += __shfl_xor(s,  m, 64);
        ss += __shfl_xor(ss, m, 64);
    }
    __shared__ float rs0[4], rs1[4];
    if (lane == 0) { rs0[wv] = s; rs1[wv] = ss; }
    __syncthreads();
    s  = rs0[0] + rs0[1] + rs0[2] + rs0[3];
    ss = rs1[0] + rs1[1] + rs1[2] + rs1[3];

    float mu  = s * (1.0f / D_MODEL);
    float var = ss * (1.0f / D_MODEL) - mu * mu;
    float rs  = rsqrtf(var + 1e-5f);

    float4 wf = *(const float4*)(w + col);
    float4 bf = *(const float4*)(b + col);
    ushort4 o;
    o.x = f2b_bits((v[0]-mu)*rs*wf.x + bf.x);
    o.y = f2b_bits((v[1]-mu)*rs*wf.y + bf.y);
    o.z = f2b_bits((v[2]-mu)*rs*wf.z + bf.z);
    o.w = f2b_bits((v[3]-mu)*rs*wf.w + bf.w);
    *(ushort4*)((unsigned short*)out + (size_t)row * D_MODEL + col) = o;
}

// ---------------------------------------------------------------------------
// MFMA GEMM (R8-proven 2-phase): C[M,N] = A[M,K]*Bw[N,K]^T + bias. Epilogues:
//   EPI 0: bias   EPI 1: bias + fast GELU   EPI 2: bias + fp32 residual
//   EPI 3: bias -> scatter bf16 Q (b,h,s,e) / K (b,h,s,e) / VT (b,h,e,s)
// 128x128 tile, 256 thr (4 waves 2x2), wave = 4x4 mfma_f32_16x16x32_bf16.
// Double-buffered 2x16KB LDS via global_load_lds; one barrier per K-step.
// bf16 C-path stages C-tile through LDS, copies out 16B/lane full rows.
// XCD-aware block remap (T1): nwg%8==0 -> bijective chunked map.
// C/D mapping (m89/m91 verified): col = lane&15, row = (lane>>4)*4 + reg.
// NOTE (R9 lesson): the 256^2 8-phase/counted-vmcnt port regressed (1 blk/CU
// + 2-half-deep pipeline exposes latency; m248 caps K=1024 gain at +10%).
// ---------------------------------------------------------------------------
template<int EPI, bool OUT_B16>
__global__ __launch_bounds__(256)
void gemm_bt(const bf16* __restrict__ A, const bf16* __restrict__ Bw,
             const float* __restrict__ bias, const float* __restrict__ resid,
             void* __restrict__ Cout, bf16* __restrict__ qb,
             bf16* __restrict__ ktb, bf16* __restrict__ vb,
             int M, int N, int K)
{
    int t    = threadIdx.x;
    int lane = t & 63, w = t >> 6;
    int wm   = w & 1,  wn = w >> 1;
    int q    = lane >> 4, r = lane & 15;

    // XCD swizzle: dispatch index L round-robins L&7 over XCDs (m09);
    // give each XCD a contiguous chunk of the original tile ordering.
    int gx  = gridDim.x;
    int L   = blockIdx.y * gx + blockIdx.x;
    int qq  = (gx * gridDim.y) >> 3;
    int nid = (L & 7) * qq + (L >> 3);
    int mb  = (nid / gx) * 128, nb = (nid % gx) * 128;

    // buf c: A at smem+c*16384 (8KB), B at +8192. C-stage reuses all 32KB.
    __shared__ char smem[32768];

    f32x4 acc[4][4] = {};

    const char* Ag = (const char*)((const unsigned short*)A + (size_t)mb * K);
    const char* Bg = (const char*)((const unsigned short*)Bw + (size_t)nb * K);

    int ar0 = t >> 2,  ac0 = (t & 3) << 3;   // row, elem-col of this thread's 16B

    int nt = K >> 5;

    #define STAGE(c, k0) do {                                      \
        char* dA = smem + (c) * 16384;                             \
        char* dB = dA + 8192;                                      \
        size_t off0 = ((size_t)ar0 * K + (k0) + ac0) * 2;          \
        size_t off1 = off0 + (size_t)64 * K * 2;                   \
        gll16(dA + t * 16,        Ag + off0);                      \
        gll16(dA + 4096 + t * 16, Ag + off1);                      \
        gll16(dB + t * 16,        Bg + off0);                      \
        gll16(dB + 4096 + t * 16, Bg + off1);                      \
    } while (0)

    STAGE(0, 0);
    __syncthreads();

    int cur = 0;
    for (int tt = 0; tt < nt; ++tt) {
        if (tt + 1 < nt) STAGE(cur ^ 1, (tt + 1) << 5);   // prefetch next tile

        const __bf16* Asb = (const __bf16*)(smem + cur * 16384);
        const __bf16* Bsb = Asb + 4096;
        bf16x8 af[4], bfr[4];
        #pragma unroll
        for (int i = 0; i < 4; i++)
            af[i] = *(const bf16x8*)(Asb + (wm * 64 + i * 16 + r) * 32 + q * 8);
        #pragma unroll
        for (int j = 0; j < 4; j++)
            bfr[j] = *(const bf16x8*)(Bsb + (wn * 64 + j * 16 + r) * 32 + q * 8);
        #pragma unroll
        for (int i = 0; i < 4; i++)
            #pragma unroll
            for (int j = 0; j < 4; j++)
                acc[i][j] = __builtin_amdgcn_mfma_f32_16x16x32_bf16(af[i], bfr[j], acc[i][j], 0, 0, 0);

        __syncthreads();   // drains vmcnt (next tile ready) + lgkm (reads done)
        cur ^= 1;
    }
    #undef STAGE

    if (OUT_B16 && EPI != 3) {
        // stage C-tile bf16 in LDS, copy out coalesced (256B rows, 16B/lane)
        __bf16* Cs = (__bf16*)smem;
        #pragma unroll
        for (int j = 0; j < 4; j++) {
            int n = nb + wn * 64 + j * 16 + r;
            float bv = bias[n];
            #pragma unroll
            for (int i = 0; i < 4; i++) {
                #pragma unroll
                for (int rr = 0; rr < 4; rr++) {
                    float v = acc[i][j][rr] + bv;
                    if (EPI == 1) v = gelu_f(v);
                    if (EPI == 2) v += resid[(size_t)(mb + wm*64 + i*16 + q*4 + rr) * N + n];
                    unsigned short ub = f2b_bits(v);
                    Cs[(wm*64 + i*16 + q*4 + rr) * 128 + wn*64 + j*16 + r] = *(__bf16*)&ub;
                }
            }
        }
        __syncthreads();
        char* Cg = (char*)Cout;
        #pragma unroll
        for (int c = 0; c < 8; c++) {
            int idx = t + c * 256;           // 2048 chunks: row = idx>>4, 16B ch
            int row = idx >> 4, ch = idx & 15;
            *(int4*)(Cg + ((size_t)(mb + row) * N + nb) * 2 + ch * 16) =
                *(const int4*)((const char*)Cs + row * 256 + ch * 16);
        }
    } else {
        #pragma unroll
        for (int j = 0; j < 4; j++) {
            int n = nb + wn * 64 + j * 16 + r;
            float bv = bias[n];
            #pragma unroll
            for (int i = 0; i < 4; i++) {
                int mbase = mb + wm * 64 + i * 16 + q * 4;
                #pragma unroll
                for (int rr = 0; rr < 4; rr++) {
                    int m = mbase + rr;
                    float v = acc[i][j][rr] + bv;
                    if (EPI == 1) v = gelu_f(v);
                    if (EPI == 2) v += resid[(size_t)m * N + n];
                    if (EPI == 3) {
                        int sect = n >> 10;
                        int h = (n >> 6) & 15;
                        int e = n & 63;
                        int bi = m >> 9, s = m & 511;
                        size_t bh = (size_t)bi * NHEAD + h;
                        bf16 val = f2b(v);
                        if (sect == 0)      qb[((bh * SEQ + s) << 6) + e] = val;
                        else if (sect == 1) ktb[((bh * SEQ + s) << 6) + e] = val;  // K rows
                        else                vb[((bh * HDIM + e) << 9) + s] = val;  // V^T
                    } else {
                        if (OUT_B16) ((bf16*)Cout)[(size_t)m * N + n] = f2b(v);
                        else         ((float*)Cout)[(size_t)m * N + n] = v;
                    }
                }
            }
        }
    }
}

// ---------------------------------------------------------------------------
// MFMA attention, TRIPLE-buffered LDS pipeline (T4 counted vmcnt).
// Grid (8,256) XCD-swizzled (R8 structure: 64 q-rows/block, K/VT L2-resident,
// FETCH ~25 MB). 256 thr = 4 waves; keys in 8 chunks of 64.
// R8's loop exposed DMA latency: its __syncthreads vmcnt(0) waited on the
// prefetch issued only ~500cy earlier. Now: prologue stages chunks 0,1;
// iter c stages chunk c+2 into buf (c+2)%3, computes chunk c from buf c%3,
// then s_waitcnt vmcnt(4) (per-wave: exactly chunk c+1's 4 DMA instrs
// retired; chunk c+2 stays in flight) -> raw s_barrier -> sched_barrier(0)
// (rule #18: pin ds_reads behind the wait). Each prefetch gets ~2 chunk-
// computes (~1000+cy) to land. REGISTER-NEUTRAL vs R8 (R10's register-funded
// variant spilled 27MB scratch). Hazards: buf (c+2)%3 overwrite of the buf
// read at c-1 is fenced by the end-of-(c-1) barrier (all ds_read results
// consumed by MFMAs before it); per-wave vmcnt before the shared barrier =>
// collective DMA visibility; P-tile is wave-private.
// Bank conflicts: both-sides involution (rule #21): linear DMA dest +
// pre-swizzled global source (granule j ^= row&7) + swizzled ds_read
// (byte ^= (row&7)<<4). One-pass no-max softmax (|s| <~ 10 << 88).
// LDS 60KB -> 2 blocks/CU; launch_bounds(256,2) (VGPR cap 256, demand ~84).
// C/D: col=lane&15, row=(lane>>4)*4+reg (m89/m91 verified).
// ---------------------------------------------------------------------------
__global__ __launch_bounds__(256, 2)
void attn_mfma(const bf16* __restrict__ Q, const bf16* __restrict__ K,
               const bf16* __restrict__ VT, const float* __restrict__ relb,
               bf16* __restrict__ out)
{
    int L   = blockIdx.x + (blockIdx.y << 3);   // grid (8,256) -> L in [0,2048)
    int xcd = L & 7, jj = L >> 3;
    int bh  = xcd * 32 + (jj >> 3);
    int q0  = (jj & 7) * 64;
    int b   = bh >> 4, h = bh & 15;
    int t = threadIdx.x, lane = t & 63, w = t >> 6;
    int l15 = lane & 15, l4 = lane >> 4;

    __shared__ int4  kvbuf4[3072];   // 48 KiB: 3 x (K-chunk 8KB + V-chunk 8KB)
    __shared__ int4  Pls4[512];      //  8 KiB P-tile [64 q][64 k], swizzled
    __shared__ float rbs[1024];      //  4 KiB rel-bias row for this head

    char* kv = (char*)kvbuf4;
    char* Pb = (char*)Pls4;
    const char* Kg = (const char*)K  + ((size_t)bh << 16);
    const char* Vg = (const char*)VT + ((size_t)bh << 16);

    #define STAGE_KV(bs, c) do {                                              \
        char* kd = kv + (bs) * 16384;                                         \
        char* vd = kd + 8192;                                                 \
        _Pragma("unroll")                                                     \
        for (int i = 0; i < 2; i++) {                                         \
            int g = t + i * 256;                                              \
            int rr_ = g >> 3;                                                 \
            int jj_ = (g & 7) ^ (rr_ & 7);                                    \
            gll16(kd + g * 16,                                                \
                  Kg + (((size_t)(c) * 64 + rr_) << 7) + (jj_ << 4));         \
            gll16(vd + g * 16,                                                \
                  Vg + ((size_t)rr_ << 10) + ((size_t)(c) << 7) + (jj_ << 4));\
        }                                                                     \
    } while (0)

    const float* rb = relb + (size_t)h * (2 * SEQ - 1);
    for (int i = t; i < 2 * SEQ - 1; i += 256) rbs[i] = rb[i];
    STAGE_KV(0, 0);
    STAGE_KV(1, 1);

    // Q fragments (16 rows per wave), loaded while stages 0,1 are in flight
    const unsigned short* Qp = (const unsigned short*)Q
        + (((size_t)bh * SEQ + q0 + w * 16 + l15) << 6) + l4 * 8;
    bf16x8 qf0 = *(const bf16x8*)Qp;
    bf16x8 qf1 = *(const bf16x8*)(Qp + 32);

    __syncthreads();   // one-time full drain: chunks 0,1 + rbs + Q all ready

    int qbase  = q0 + w * 16 + l4 * 4;
    int prow   = w * 16 + l15;
    int prbase = prow << 7;
    int pswz   = (prow & 7) << 4;
    float sum[4] = {0.f, 0.f, 0.f, 0.f};
    f32x4 oacc[4] = {};

    for (int c = 0; c < 8; ++c) {
        if (c + 2 < 8) STAGE_KV((c + 2) % 3, c + 2);   // depth-2 prefetch

        const char* Kl = kv + (c % 3) * 16384;
        const char* Vl = Kl + 8192;

        f32x4 sc[4];
        #pragma unroll
        for (int kt = 0; kt < 4; kt++) {
            int row = kt * 16 + l15;
            int swz = (row & 7) << 4;
            bf16x8 kf0 = *(const bf16x8*)(Kl + (((row << 7) + (l4 << 4)) ^ swz));
            bf16x8 kf1 = *(const bf16x8*)(Kl + (((row << 7) + 64 + (l4 << 4)) ^ swz));
            f32x4 a = {};
            a = __builtin_amdgcn_mfma_f32_16x16x32_bf16(qf0, kf0, a, 0, 0, 0);
            a = __builtin_amdgcn_mfma_f32_16x16x32_bf16(qf1, kf1, a, 0, 0, 0);
            sc[kt] = a;
        }

        #pragma unroll
        for (int kt = 0; kt < 4; kt++) {
            int relbase = qbase - (c * 64 + kt * 16 + l15) + (SEQ - 1);
            #pragma unroll
            for (int reg = 0; reg < 4; reg++) {
                float p = __expf(sc[kt][reg] * 0.125f + rbs[relbase + reg]);
                sum[reg] += p;
                float o = __shfl_xor(p, 1, 64);
                unsigned lo = f2b_bits((lane & 1) ? o : p);
                unsigned hi = f2b_bits((lane & 1) ? p : o);
                unsigned pk = lo | (hi << 16);
                if ((lane & 1) == (reg >> 1)) {      // even lanes: reg 0,1; odd: 2,3
                    int row  = w * 16 + l4 * 4 + reg;
                    int byte = ((row << 7) + (kt << 5) + ((l15 & ~1) << 1))
                             ^ ((row & 7) << 4);
                    *(unsigned*)(Pb + byte) = pk;
                }
            }
        }

        #pragma unroll
        for (int k2 = 0; k2 < 2; k2++) {
            int pbyte = (prbase + (k2 << 6) + (l4 << 4)) ^ pswz;
            bf16x8 pf = *(const bf16x8*)(Pb + pbyte);
            #pragma unroll
            for (int et = 0; et < 4; et++) {
                int vrow = et * 16 + l15;
                bf16x8 vf = *(const bf16x8*)
                    (Vl + (((vrow << 7) + (k2 << 6) + (l4 << 4)) ^ ((vrow & 7) << 4)));
                oacc[et] = __builtin_amdgcn_mfma_f32_16x16x32_bf16(pf, vf, oacc[et], 0, 0, 0);
            }
        }

        // counted wait: chunk c+1's 4 DMA instrs retired (chunk c+2 in flight)
        if (c < 6)       asm volatile("s_waitcnt vmcnt(4)" ::: "memory");
        else if (c == 6) asm volatile("s_waitcnt vmcnt(0)" ::: "memory");
        if (c < 7) {
            __builtin_amdgcn_s_barrier();
            __builtin_amdgcn_sched_barrier(0);   // pin ds_reads behind the wait
        }
    }
    #undef STAGE_KV

    #pragma unroll
    for (int m = 1; m < 16; m <<= 1)
        #pragma unroll
        for (int reg = 0; reg < 4; reg++)
            sum[reg] += __shfl_xor(sum[reg], m, 64);
    float rcp[4];
    #pragma unroll
    for (int reg = 0; reg < 4; reg++) rcp[reg] = 1.0f / sum[reg];

    bf16* op = out + (size_t)(b * SEQ + q0 + w * 16 + l4 * 4) * D_MODEL
             + h * HDIM + l15;
    #pragma unroll
    for (int et = 0; et < 4; et++)
        #pragma unroll
        for (int reg = 0; reg < 4; reg++)
            op[(size_t)reg * D_MODEL + et * 16] = f2b(oacc[et][reg] * rcp[reg]);
}

// ---------------------------------------------------------------------------
// Launch. Inputs fp32 (dict order), OUTPUT fp32 (reference dtype).
// ws peak 121 MiB:
//   [1,7)   wqkv_b  [7,9) wo_b     (live through step 5)
//   [1,9)   w1_b    (cvt after Wo gemm)    [9,17) w2_b (cvt after w1 gemm)
//   [9,25)  xn -> xn2
//   [25,41) Q  [41,57) K  -> x1 fp32 [25,57) after attention
//   [57,121) hid bf16 8192x4096
// d_out scratch: VT bf16 [0,16M), att bf16 [16M,32M).
// ---------------------------------------------------------------------------
extern "C" void kernel_launch(void* const* d_in, const int* in_sizes, int n_in,
                              void* d_out, int out_size, void* d_ws, size_t ws_size,
                              hipStream_t stream)
{
    const float* x    = (const float*)d_in[0];
    const float* wqkv = (const float*)d_in[1];
    const float* bqkv = (const float*)d_in[2];
    const float* wo   = (const float*)d_in[3];
    const float* bo   = (const float*)d_in[4];
    const float* relb = (const float*)d_in[5];
    const float* w1   = (const float*)d_in[6];
    const float* b1   = (const float*)d_in[7];
    const float* w2   = (const float*)d_in[8];
    const float* b2   = (const float*)d_in[9];
    const float* ln1w = (const float*)d_in[10];
    const float* ln1b = (const float*)d_in[11];
    const float* ln2w = (const float*)d_in[12];
    const float* ln2b = (const float*)d_in[13];

    char* ws = (char*)d_ws;
    const size_t MB = 1048576;
    bf16*  wqkv_b = (bf16*)(ws + 1 * MB);
    bf16*  wo_b   = (bf16*)(ws + 7 * MB);
    bf16*  xn     = (bf16*)(ws + 9 * MB);
    bf16*  Qb     = (bf16*)(ws + 25 * MB);
    bf16*  Kb     = (bf16*)(ws + 41 * MB);
    float* x1     = (float*)(ws + 25 * MB);  // over dead Q+K, 32 MiB
    bf16*  w1_b   = (bf16*)(ws + 1 * MB);    // over dead wqkv_b+wo_b (step 6)
    bf16*  w2_b   = (bf16*)(ws + 9 * MB);    // over dead xn2 (step 9)
    bf16*  xn2    = (bf16*)(ws + 9 * MB);    // over dead xn
    bf16*  hid    = (bf16*)(ws + 57 * MB);   // 8192x4096 bf16, 64 MiB
    bf16*  VT     = (bf16*)d_out;                       // d_out[0,16M)
    bf16*  att    = (bf16*)((char*)d_out + 16 * MB);    // d_out[16M,32M)
    float* out    = (float*)d_out;

    // 1. attention-path weights fp32 -> bf16
    cvt_kernel<<<3072, 256, 0, stream>>>(wqkv, wqkv_b, 3 * D_MODEL * D_MODEL);
    cvt_kernel<<<1024, 256, 0, stream>>>(wo,   wo_b,   D_MODEL * D_MODEL);
    // 2. xn = LN1(x)
    ln_kernel<<<MROWS, 256, 0, stream>>>(x, ln1w, ln1b, xn);
    // 3. qkv projection scattered into Q / K / VT(=d_out scratch)
    gemm_bt<3,true><<<dim3(24, 64), 256, 0, stream>>>(xn, wqkv_b, bqkv, nullptr,
        nullptr, Qb, Kb, VT, MROWS, 3 * D_MODEL, D_MODEL);
    // 4. MFMA attention -> att (d_out scratch, bf16)
    attn_mfma<<<dim3(8, 256), 256, 0, stream>>>(Qb, Kb, VT, relb, att);
    // 5. x1 = x + att @ Wo^T + bo   (fp32, over dead Q+K)
    gemm_bt<2,false><<<dim3(8, 64), 256, 0, stream>>>(att, wo_b, bo, x,
        x1, nullptr, nullptr, nullptr, MROWS, D_MODEL, D_MODEL);
    // 6. w1 -> bf16 (over dead wqkv_b+wo_b)
    cvt_kernel<<<4096, 256, 0, stream>>>(w1, w1_b, DFF * D_MODEL);
    // 7. xn2 = LN2(x1)   (over dead xn)
    ln_kernel<<<MROWS, 256, 0, stream>>>(x1, ln2w, ln2b, xn2);
    // 8. hid = GELU(xn2 @ w1^T + b1), full M: 2048 blocks
    gemm_bt<1,true><<<dim3(32, 64), 256, 0, stream>>>(xn2, w1_b, b1, nullptr,
        hid, nullptr, nullptr, nullptr, MROWS, DFF, D_MODEL);
    // 9. w2 -> bf16 (over dead xn2)
    cvt_kernel<<<4096, 256, 0, stream>>>(w2, w2_b, D_MODEL * DFF);
    // 10. out = x1 + hid @ w2^T + b2, full M: 512 blocks, fp32 into d_out
    gemm_bt<2,false><<<dim3(8, 64), 256, 0, stream>>>(hid, w2_b, b2, x1,
        out, nullptr, nullptr, nullptr, MROWS, D_MODEL, DFF);
}

// Round 12
// 503.377 us; speedup vs baseline: 1.3199x; 1.0573x over previous
//
#include <hip/hip_runtime.h>
#include <hip/hip_bf16.h>
#include <stdint.h>

typedef __hip_bfloat16 bf16;
typedef __attribute__((ext_vector_type(8))) __bf16 bf16x8;
typedef __attribute__((ext_vector_type(4))) float f32x4;

#define D_MODEL 1024
#define NHEAD   16
#define HDIM    64
#define DFF     4096
#define BATCH   16
#define SEQ     512
#define MROWS   (BATCH*SEQ)   // 8192

__device__ __forceinline__ float b2f_bits(unsigned short u) {
    return __uint_as_float(((unsigned)u) << 16);
}
__device__ __forceinline__ bf16 f2b(float v) { return __float2bfloat16(v); }
__device__ __forceinline__ unsigned short f2b_bits(float v) {
    bf16 t = __float2bfloat16(v);
    return *(unsigned short*)&t;
}
// async global->LDS, 16B per lane (dest = wave-uniform base + lane*16)
__device__ __forceinline__ void gll16(void* lds, const void* gsrc) {
    __builtin_amdgcn_global_load_lds(
        (const __attribute__((address_space(1))) unsigned*)gsrc,
        (__attribute__((address_space(3))) unsigned*)lds,
        16, 0, 0);
}
// exact-enough GELU: tanh form, max |err| ~3e-4 vs erf form (ok at bf16 out)
__device__ __forceinline__ float gelu_f(float u) {
    float z  = 0.7978845608028654f * (u + 0.044715f * u * u * u);
    float az = fabsf(z);
    float e  = __expf(-2.0f * az);
    float th = (1.0f - e) / (1.0f + e);
    th = copysignf(th, z);
    return 0.5f * u * (1.0f + th);
}

// ---------------------------------------------------------------------------
// fp32 -> bf16 weight conversion (n multiple of 4; grid covers exactly n/4)
// ---------------------------------------------------------------------------
__global__ __launch_bounds__(256)
void cvt_kernel(const float* __restrict__ in, bf16* __restrict__ out, int n)
{
    int i = (blockIdx.x * 256 + threadIdx.x) * 4;
    if (i >= n) return;
    float4 f = *(const float4*)(in + i);
    ushort4 o;
    o.x = f2b_bits(f.x); o.y = f2b_bits(f.y);
    o.z = f2b_bits(f.z); o.w = f2b_bits(f.w);
    *(ushort4*)((unsigned short*)out + i) = o;
}

// ---------------------------------------------------------------------------
// LayerNorm: fp32 in, bf16 out. One block (256 threads) per row of 1024.
// ---------------------------------------------------------------------------
__global__ __launch_bounds__(256)
void ln_kernel(const float* __restrict__ xin, const float* __restrict__ w,
               const float* __restrict__ b, bf16* __restrict__ out)
{
    int row  = blockIdx.x;
    int t    = threadIdx.x;
    int lane = t & 63, wv = t >> 6;
    int col  = t * 4;

    float4 f = *(const float4*)(xin + (size_t)row * D_MODEL + col);
    float v[4] = {f.x, f.y, f.z, f.w};

    float s  = v[0] + v[1] + v[2] + v[3];
    float ss = v[0]*v[0] + v[1]*v[1] + v[2]*v[2] + v[3]*v[3];
    #pragma unroll
    for (int m = 1; m < 64; m <<= 1) {
        s  += __shfl_xor(s,  m, 64);
        ss += __shfl_xor(ss, m, 64);
    }
    __shared__ float rs0[4], rs1[4];
    if (lane == 0) { rs0[wv] = s; rs1[wv] = ss; }
    __syncthreads();
    s  = rs0[0] + rs0[1] + rs0[2] + rs0[3];
    ss = rs1[0] + rs1[1] + rs1[2] + rs1[3];

    float mu  = s * (1.0f / D_MODEL);
    float var = ss * (1.0f / D_MODEL) - mu * mu;
    float rs  = rsqrtf(var + 1e-5f);

    float4 wf = *(const float4*)(w + col);
    float4 bf = *(const float4*)(b + col);
    ushort4 o;
    o.x = f2b_bits((v[0]-mu)*rs*wf.x + bf.x);
    o.y = f2b_bits((v[1]-mu)*rs*wf.y + bf.y);
    o.z = f2b_bits((v[2]-mu)*rs*wf.z + bf.z);
    o.w = f2b_bits((v[3]-mu)*rs*wf.w + bf.w);
    *(ushort4*)((unsigned short*)out + (size_t)row * D_MODEL + col) = o;
}

// ---------------------------------------------------------------------------
// MFMA GEMM (R8-proven 2-phase): C[M,N] = A[M,K]*Bw[N,K]^T + bias. Epilogues:
//   EPI 0: bias   EPI 1: bias + fast GELU   EPI 2: bias + fp32 residual
//   EPI 3: bias -> scatter bf16 Q (b,h,s,e) / K (b,h,s,e) / VT (b,h,e,s)
//     Q/K blocks (nb<2048): LDS-staged coalesced 16B writes (e is fast axis;
//     a 128-col tile lies in one section since 1024%128==0). V blocks keep
//     the direct scatter (4-consecutive-s stores merge).
// 128x128 tile, 256 thr (4 waves 2x2), wave = 4x4 mfma_f32_16x16x32_bf16.
// Double-buffered 2x16KB LDS via global_load_lds; one barrier per K-step.
// bf16 C-path stages C-tile through LDS, copies out 16B/lane full rows.
// XCD-aware block remap (T1): nwg%8==0 -> bijective chunked map.
// C/D mapping (m89/m91 verified): col = lane&15, row = (lane>>4)*4 + reg.
// NOTE (R9 lesson): the 256^2 8-phase/counted-vmcnt port regressed (1 blk/CU
// + 2-half-deep pipeline exposes latency; m248 caps K=1024 gain at +10%).
// ---------------------------------------------------------------------------
template<int EPI, bool OUT_B16>
__global__ __launch_bounds__(256)
void gemm_bt(const bf16* __restrict__ A, const bf16* __restrict__ Bw,
             const float* __restrict__ bias, const float* __restrict__ resid,
             void* __restrict__ Cout, bf16* __restrict__ qb,
             bf16* __restrict__ ktb, bf16* __restrict__ vb,
             int M, int N, int K)
{
    int t    = threadIdx.x;
    int lane = t & 63, w = t >> 6;
    int wm   = w & 1,  wn = w >> 1;
    int q    = lane >> 4, r = lane & 15;

    // XCD swizzle: dispatch index L round-robins L&7 over XCDs (m09);
    // give each XCD a contiguous chunk of the original tile ordering.
    int gx  = gridDim.x;
    int L   = blockIdx.y * gx + blockIdx.x;
    int qq  = (gx * gridDim.y) >> 3;
    int nid = (L & 7) * qq + (L >> 3);
    int mb  = (nid / gx) * 128, nb = (nid % gx) * 128;

    // buf c: A at smem+c*16384 (8KB), B at +8192. C-stage reuses all 32KB.
    __shared__ char smem[32768];

    f32x4 acc[4][4] = {};

    const char* Ag = (const char*)((const unsigned short*)A + (size_t)mb * K);
    const char* Bg = (const char*)((const unsigned short*)Bw + (size_t)nb * K);

    int ar0 = t >> 2,  ac0 = (t & 3) << 3;   // row, elem-col of this thread's 16B

    int nt = K >> 5;

    #define STAGE(c, k0) do {                                      \
        char* dA = smem + (c) * 16384;                             \
        char* dB = dA + 8192;                                      \
        size_t off0 = ((size_t)ar0 * K + (k0) + ac0) * 2;          \
        size_t off1 = off0 + (size_t)64 * K * 2;                   \
        gll16(dA + t * 16,        Ag + off0);                      \
        gll16(dA + 4096 + t * 16, Ag + off1);                      \
        gll16(dB + t * 16,        Bg + off0);                      \
        gll16(dB + 4096 + t * 16, Bg + off1);                      \
    } while (0)

    STAGE(0, 0);
    __syncthreads();

    int cur = 0;
    for (int tt = 0; tt < nt; ++tt) {
        if (tt + 1 < nt) STAGE(cur ^ 1, (tt + 1) << 5);   // prefetch next tile

        const __bf16* Asb = (const __bf16*)(smem + cur * 16384);
        const __bf16* Bsb = Asb + 4096;
        bf16x8 af[4], bfr[4];
        #pragma unroll
        for (int i = 0; i < 4; i++)
            af[i] = *(const bf16x8*)(Asb + (wm * 64 + i * 16 + r) * 32 + q * 8);
        #pragma unroll
        for (int j = 0; j < 4; j++)
            bfr[j] = *(const bf16x8*)(Bsb + (wn * 64 + j * 16 + r) * 32 + q * 8);
        #pragma unroll
        for (int i = 0; i < 4; i++)
            #pragma unroll
            for (int j = 0; j < 4; j++)
                acc[i][j] = __builtin_amdgcn_mfma_f32_16x16x32_bf16(af[i], bfr[j], acc[i][j], 0, 0, 0);

        __syncthreads();   // drains vmcnt (next tile ready) + lgkm (reads done)
        cur ^= 1;
    }
    #undef STAGE

    if (EPI == 3) {
        if (nb < 2048) {
            // Q/K: stage C-tile in LDS, write coalesced 16B chunks.
            __bf16* Cs = (__bf16*)smem;
            #pragma unroll
            for (int j = 0; j < 4; j++) {
                int n = nb + wn * 64 + j * 16 + r;
                float bv = bias[n];
                #pragma unroll
                for (int i = 0; i < 4; i++)
                    #pragma unroll
                    for (int rr = 0; rr < 4; rr++) {
                        unsigned short ub = f2b_bits(acc[i][j][rr] + bv);
                        Cs[(wm*64 + i*16 + q*4 + rr) * 128 + wn*64 + j*16 + r] = *(__bf16*)&ub;
                    }
            }
            __syncthreads();
            bf16* dst = (nb >> 10) ? ktb : qb;
            #pragma unroll
            for (int p = 0; p < 8; p++) {
                int idx = t + p * 256;             // 2048 chunks of 16B
                int row = idx >> 4, ch = idx & 15;
                int n  = nb + ch * 8;
                int hh = (n >> 6) & 15, e0 = n & 63;
                int m  = mb + row, bi = m >> 9, s = m & 511;
                *(int4*)(dst + ((((size_t)bi * 16 + hh) * 512 + s) << 6) + e0) =
                    *(const int4*)(Cs + row * 128 + ch * 8);
            }
        } else {
            // V^T: direct scatter (4 consecutive-s 2B stores merge to 8B)
            #pragma unroll
            for (int j = 0; j < 4; j++) {
                int n = nb + wn * 64 + j * 16 + r;
                float bv = bias[n];
                int h = (n >> 6) & 15, e = n & 63;
                #pragma unroll
                for (int i = 0; i < 4; i++) {
                    int mbase = mb + wm * 64 + i * 16 + q * 4;
                    #pragma unroll
                    for (int rr = 0; rr < 4; rr++) {
                        int m = mbase + rr;
                        int bi = m >> 9, s = m & 511;
                        size_t bh = (size_t)bi * NHEAD + h;
                        vb[((bh * HDIM + e) << 9) + s] = f2b(acc[i][j][rr] + bv);
                    }
                }
            }
        }
    } else if (OUT_B16) {
        // stage C-tile bf16 in LDS, copy out coalesced (256B rows, 16B/lane)
        __bf16* Cs = (__bf16*)smem;
        #pragma unroll
        for (int j = 0; j < 4; j++) {
            int n = nb + wn * 64 + j * 16 + r;
            float bv = bias[n];
            #pragma unroll
            for (int i = 0; i < 4; i++) {
                #pragma unroll
                for (int rr = 0; rr < 4; rr++) {
                    float v = acc[i][j][rr] + bv;
                    if (EPI == 1) v = gelu_f(v);
                    if (EPI == 2) v += resid[(size_t)(mb + wm*64 + i*16 + q*4 + rr) * N + n];
                    unsigned short ub = f2b_bits(v);
                    Cs[(wm*64 + i*16 + q*4 + rr) * 128 + wn*64 + j*16 + r] = *(__bf16*)&ub;
                }
            }
        }
        __syncthreads();
        char* Cg = (char*)Cout;
        #pragma unroll
        for (int c = 0; c < 8; c++) {
            int idx = t + c * 256;           // 2048 chunks: row = idx>>4, 16B ch
            int row = idx >> 4, ch = idx & 15;
            *(int4*)(Cg + ((size_t)(mb + row) * N + nb) * 2 + ch * 16) =
                *(const int4*)((const char*)Cs + row * 256 + ch * 16);
        }
    } else {
        #pragma unroll
        for (int j = 0; j < 4; j++) {
            int n = nb + wn * 64 + j * 16 + r;
            float bv = bias[n];
            #pragma unroll
            for (int i = 0; i < 4; i++) {
                int mbase = mb + wm * 64 + i * 16 + q * 4;
                #pragma unroll
                for (int rr = 0; rr < 4; rr++) {
                    int m = mbase + rr;
                    float v = acc[i][j][rr] + bv;
                    if (EPI == 1) v = gelu_f(v);
                    if (EPI == 2) v += resid[(size_t)m * N + n];
                    ((float*)Cout)[(size_t)m * N + n] = v;
                }
            }
        }
    }
}

// ---------------------------------------------------------------------------
// MFMA attention (R8 structure, 4 blocks/CU). Grid (8,256) XCD-swizzled
// (K/VT L2-resident, FETCH ~25 MB). 256 thr = 4 waves; wave = 16 q-rows;
// keys in 8 chunks of 64, double-buffered DMA K/V^T staging (zero data
// VGPRs), one barrier per chunk. rel-bias read DIRECTLY from global
// (16 consecutive-descending 4B addrs per quarter-wave = 64B segments,
// 4KB/head, L1/L2-resident) -> LDS exactly 40960B -> 4 blocks/CU
// (4 x 40960 = 163840 = 160 KiB exactly). R6/R7/R10/R11 established the
// kernel is serial-chain latency-bound and only blocks/CU has ever moved
// it (2->3 blocks = 139->104 us); this buys the 4th block register-free.
// launch_bounds(256,4): demand ~90 VGPR << 128 cap (not R2's 244 -> safe).
// Bank conflicts: both-sides involution (rule #21). One-pass no-max
// softmax (|s| <~ 10 << 88). C/D: col=lane&15, row=(lane>>4)*4+reg.
// ---------------------------------------------------------------------------
__global__ __launch_bounds__(256, 4)
void attn_mfma(const bf16* __restrict__ Q, const bf16* __restrict__ K,
               const bf16* __restrict__ VT, const float* __restrict__ relb,
               bf16* __restrict__ out)
{
    int L   = blockIdx.x + (blockIdx.y << 3);   // grid (8,256) -> L in [0,2048)
    int xcd = L & 7, jj = L >> 3;
    int bh  = xcd * 32 + (jj >> 3);
    int q0  = (jj & 7) * 64;
    int b   = bh >> 4, h = bh & 15;
    int t = threadIdx.x, lane = t & 63, w = t >> 6;
    int l15 = lane & 15, l4 = lane >> 4;

    __shared__ int4  kvbuf4[2048];   // 32 KiB: 2 x (K-chunk 8KB + V-chunk 8KB)
    __shared__ int4  Pls4[512];      //  8 KiB P-tile [64 q][64 k], swizzled

    char* kv = (char*)kvbuf4;
    char* Pb = (char*)Pls4;
    const char* Kg = (const char*)K  + ((size_t)bh << 16);
    const char* Vg = (const char*)VT + ((size_t)bh << 16);
    const float* rb = relb + (size_t)h * (2 * SEQ - 1);

    #define STAGE_KV(bs, c) do {                                              \
        char* kd = kv + (bs) * 16384;                                         \
        char* vd = kd + 8192;                                                 \
        _Pragma("unroll")                                                     \
        for (int i = 0; i < 2; i++) {                                         \
            int g = t + i * 256;                                              \
            int rr_ = g >> 3;                                                 \
            int jj_ = (g & 7) ^ (rr_ & 7);                                    \
            gll16(kd + g * 16,                                                \
                  Kg + (((size_t)(c) * 64 + rr_) << 7) + (jj_ << 4));         \
            gll16(vd + g * 16,                                                \
                  Vg + ((size_t)rr_ << 10) + ((size_t)(c) << 7) + (jj_ << 4));\
        }                                                                     \
    } while (0)

    STAGE_KV(0, 0);

    // Q fragments (16 rows per wave), loaded while stage 0 is in flight
    const unsigned short* Qp = (const unsigned short*)Q
        + (((size_t)bh * SEQ + q0 + w * 16 + l15) << 6) + l4 * 8;
    bf16x8 qf0 = *(const bf16x8*)Qp;
    bf16x8 qf1 = *(const bf16x8*)(Qp + 32);

    __syncthreads();   // stage 0 visible

    int qbase  = q0 + w * 16 + l4 * 4;         // + reg = this lane's score rows
    int prow   = w * 16 + l15;                 // PV A-frag read row
    int prbase = prow << 7;                    // 128 B row stride
    int pswz   = (prow & 7) << 4;
    float sum[4] = {0.f, 0.f, 0.f, 0.f};
    f32x4 oacc[4] = {};

    int cur = 0;
    for (int c = 0; c < 8; ++c) {
        if (c < 7) STAGE_KV(cur ^ 1, c + 1);   // DMA next chunk (no VGPRs)

        const char* Kl = kv + cur * 16384;
        const char* Vl = Kl + 8192;

        // ---- QK^T: 4 key-tiles of 16, 2 MFMAs each (K=64) ----
        f32x4 sc[4];
        #pragma unroll
        for (int kt = 0; kt < 4; kt++) {
            int row = kt * 16 + l15;
            int swz = (row & 7) << 4;
            bf16x8 kf0 = *(const bf16x8*)(Kl + (((row << 7) + (l4 << 4)) ^ swz));
            bf16x8 kf1 = *(const bf16x8*)(Kl + (((row << 7) + 64 + (l4 << 4)) ^ swz));
            f32x4 a = {};
            a = __builtin_amdgcn_mfma_f32_16x16x32_bf16(qf0, kf0, a, 0, 0, 0);
            a = __builtin_amdgcn_mfma_f32_16x16x32_bf16(qf1, kf1, a, 0, 0, 0);
            sc[kt] = a;
        }

        // ---- bias(global, L1-hit) + exp + sum + pack -> swizzled P ----
        #pragma unroll
        for (int kt = 0; kt < 4; kt++) {
            int relbase = qbase - (c * 64 + kt * 16 + l15) + (SEQ - 1);
            #pragma unroll
            for (int reg = 0; reg < 4; reg++) {
                float p = __expf(sc[kt][reg] * 0.125f + rb[relbase + reg]);
                sum[reg] += p;
                float o = __shfl_xor(p, 1, 64);
                unsigned lo = f2b_bits((lane & 1) ? o : p);
                unsigned hi = f2b_bits((lane & 1) ? p : o);
                unsigned pk = lo | (hi << 16);
                if ((lane & 1) == (reg >> 1)) {      // even lanes: reg 0,1; odd: 2,3
                    int row  = w * 16 + l4 * 4 + reg;
                    int byte = ((row << 7) + (kt << 5) + ((l15 & ~1) << 1))
                             ^ ((row & 7) << 4);
                    *(unsigned*)(Pb + byte) = pk;
                }
            }
        }

        // ---- PV: 2 k-slices of 32 keys x 4 e-tiles ----
        #pragma unroll
        for (int k2 = 0; k2 < 2; k2++) {
            int pbyte = (prbase + (k2 << 6) + (l4 << 4)) ^ pswz;
            bf16x8 pf = *(const bf16x8*)(Pb + pbyte);
            #pragma unroll
            for (int et = 0; et < 4; et++) {
                int vrow = et * 16 + l15;
                bf16x8 vf = *(const bf16x8*)
                    (Vl + (((vrow << 7) + (k2 << 6) + (l4 << 4)) ^ ((vrow & 7) << 4)));
                oacc[et] = __builtin_amdgcn_mfma_f32_16x16x32_bf16(pf, vf, oacc[et], 0, 0, 0);
            }
        }

        __syncthreads();   // stage c+1 landed; all waves done reading buf cur
        cur ^= 1;
    }
    #undef STAGE_KV

    #pragma unroll
    for (int m = 1; m < 16; m <<= 1)
        #pragma unroll
        for (int reg = 0; reg < 4; reg++)
            sum[reg] += __shfl_xor(sum[reg], m, 64);
    float rcp[4];
    #pragma unroll
    for (int reg = 0; reg < 4; reg++) rcp[reg] = 1.0f / sum[reg];

    bf16* op = out + (size_t)(b * SEQ + q0 + w * 16 + l4 * 4) * D_MODEL
             + h * HDIM + l15;
    #pragma unroll
    for (int et = 0; et < 4; et++)
        #pragma unroll
        for (int reg = 0; reg < 4; reg++)
            op[(size_t)reg * D_MODEL + et * 16] = f2b(oacc[et][reg] * rcp[reg]);
}

// ---------------------------------------------------------------------------
// Launch. Inputs fp32 (dict order), OUTPUT fp32 (reference dtype).
// ws peak 121 MiB:
//   [1,7)   wqkv_b  [7,9) wo_b     (live through step 5)
//   [1,9)   w1_b    (cvt after Wo gemm)    [9,17) w2_b (cvt after w1 gemm)
//   [9,25)  xn -> xn2
//   [25,41) Q  [41,57) K  -> x1 fp32 [25,57) after attention
//   [57,121) hid bf16 8192x4096
// d_out scratch: VT bf16 [0,16M), att bf16 [16M,32M).
// ---------------------------------------------------------------------------
extern "C" void kernel_launch(void* const* d_in, const int* in_sizes, int n_in,
                              void* d_out, int out_size, void* d_ws, size_t ws_size,
                              hipStream_t stream)
{
    const float* x    = (const float*)d_in[0];
    const float* wqkv = (const float*)d_in[1];
    const float* bqkv = (const float*)d_in[2];
    const float* wo   = (const float*)d_in[3];
    const float* bo   = (const float*)d_in[4];
    const float* relb = (const float*)d_in[5];
    const float* w1   = (const float*)d_in[6];
    const float* b1   = (const float*)d_in[7];
    const float* w2   = (const float*)d_in[8];
    const float* b2   = (const float*)d_in[9];
    const float* ln1w = (const float*)d_in[10];
    const float* ln1b = (const float*)d_in[11];
    const float* ln2w = (const float*)d_in[12];
    const float* ln2b = (const float*)d_in[13];

    char* ws = (char*)d_ws;
    const size_t MB = 1048576;
    bf16*  wqkv_b = (bf16*)(ws + 1 * MB);
    bf16*  wo_b   = (bf16*)(ws + 7 * MB);
    bf16*  xn     = (bf16*)(ws + 9 * MB);
    bf16*  Qb     = (bf16*)(ws + 25 * MB);
    bf16*  Kb     = (bf16*)(ws + 41 * MB);
    float* x1     = (float*)(ws + 25 * MB);  // over dead Q+K, 32 MiB
    bf16*  w1_b   = (bf16*)(ws + 1 * MB);    // over dead wqkv_b+wo_b (step 6)
    bf16*  w2_b   = (bf16*)(ws + 9 * MB);    // over dead xn2 (step 9)
    bf16*  xn2    = (bf16*)(ws + 9 * MB);    // over dead xn
    bf16*  hid    = (bf16*)(ws + 57 * MB);   // 8192x4096 bf16, 64 MiB
    bf16*  VT     = (bf16*)d_out;                       // d_out[0,16M)
    bf16*  att    = (bf16*)((char*)d_out + 16 * MB);    // d_out[16M,32M)
    float* out    = (float*)d_out;

    // 1. attention-path weights fp32 -> bf16
    cvt_kernel<<<3072, 256, 0, stream>>>(wqkv, wqkv_b, 3 * D_MODEL * D_MODEL);
    cvt_kernel<<<1024, 256, 0, stream>>>(wo,   wo_b,   D_MODEL * D_MODEL);
    // 2. xn = LN1(x)
    ln_kernel<<<MROWS, 256, 0, stream>>>(x, ln1w, ln1b, xn);
    // 3. qkv projection scattered into Q / K / VT(=d_out scratch)
    gemm_bt<3,true><<<dim3(24, 64), 256, 0, stream>>>(xn, wqkv_b, bqkv, nullptr,
        nullptr, Qb, Kb, VT, MROWS, 3 * D_MODEL, D_MODEL);
    // 4. MFMA attention -> att (d_out scratch, bf16)
    attn_mfma<<<dim3(8, 256), 256, 0, stream>>>(Qb, Kb, VT, relb, att);
    // 5. x1 = x + att @ Wo^T + bo   (fp32, over dead Q+K)
    gemm_bt<2,false><<<dim3(8, 64), 256, 0, stream>>>(att, wo_b, bo, x,
        x1, nullptr, nullptr, nullptr, MROWS, D_MODEL, D_MODEL);
    // 6. w1 -> bf16 (over dead wqkv_b+wo_b)
    cvt_kernel<<<4096, 256, 0, stream>>>(w1, w1_b, DFF * D_MODEL);
    // 7. xn2 = LN2(x1)   (over dead xn)
    ln_kernel<<<MROWS, 256, 0, stream>>>(x1, ln2w, ln2b, xn2);
    // 8. hid = GELU(xn2 @ w1^T + b1), full M: 2048 blocks
    gemm_bt<1,true><<<dim3(32, 64), 256, 0, stream>>>(xn2, w1_b, b1, nullptr,
        hid, nullptr, nullptr, nullptr, MROWS, DFF, D_MODEL);
    // 9. w2 -> bf16 (over dead xn2)
    cvt_kernel<<<4096, 256, 0, stream>>>(w2, w2_b, D_MODEL * DFF);
    // 10. out = x1 + hid @ w2^T + b2, full M: 512 blocks, fp32 into d_out
    gemm_bt<2,false><<<dim3(8, 64), 256, 0, stream>>>(hid, w2_b, b2, x1,
        out, nullptr, nullptr, nullptr, MROWS, D_MODEL, DFF);
}